// Round 8
// baseline (4067.139 us; speedup 1.0000x reference)
//
#include <hip/hip_runtime.h>

#define S_LEN 128
#define T_LEN 64
#define BSZ   64
#define EMBD  256
#define HID_  512
#define DHID_ 1024
#define VOC_  32000
#define HSTR  1024

typedef float  f4_t  __attribute__((ext_vector_type(4)));
typedef float  f32x4 __attribute__((ext_vector_type(4)));
typedef short  s16x8 __attribute__((ext_vector_type(8)));
typedef __bf16 bf16x8 __attribute__((ext_vector_type(8)));
typedef unsigned short u16x4 __attribute__((ext_vector_type(4)));
typedef int    i32x2 __attribute__((ext_vector_type(2)));

// ---------------- workspace layout ----------------
// float offsets:
#define WS_CS   0ull                       // 131,072 fl (2 layers x (B,HSTR) fp32 c-state)
#define WS_BAR  (WS_CS + 131072ull)        // 65,536 ints (4 regions x 16384)
#define WS_BF   (WS_BAR + 65536ull)
// ushort offsets within bf16 region:
#define U_X0B   0ull                        // 2,097,152
#define U_HE0   (U_X0B  + 2097152ull)       // 8,388,608
#define U_HE1   (U_HE0  + 8388608ull)       // 8,388,608
#define U_HD0   (U_HE1  + 8388608ull)       // 4,194,304
#define U_HD1   (U_HD0  + 4194304ull)       // 4,194,304
#define U_HSB   (U_HD1  + 4194304ull)       // 131,072
#define U_E0W   (U_HSB  + 131072ull)        // 1,048,576
#define U_E1W   (U_E0W  + 1048576ull)       // 4,194,304
#define U_D0W   (U_E1W  + 4194304ull)       // 1,048,576
#define U_D1W   (U_D0W  + 1048576ull)       // 4,194,304
#define U_XWA   (U_D1W  + 4194304ull)       // 16,777,216 (bf16 xw, (T,4H,B))
#define U_XWB   (U_XWA  + 16777216ull)      // 16,777,216
#define U_WOUT  (U_XWB  + 16777216ull)      // 32,768,000

__device__ __forceinline__ unsigned short f2bf(float x) {
    unsigned u = __builtin_bit_cast(unsigned, x);
    return (unsigned short)((u + 0x7fffu + ((u >> 16) & 1u)) >> 16);
}
__device__ __forceinline__ float bf2f(unsigned u) {
    return __builtin_bit_cast(float, u << 16);
}

// ---------------- coherent (LLC-scope) memory helpers ----------------
__device__ __forceinline__ f4_t sc_load4(const void* p) {
    f4_t v;
    asm volatile("global_load_dwordx4 %0, %1, off sc0 sc1" : "=v"(v) : "v"(p));
    return v;                               // NOT ready until a vmcnt wait
}
__device__ __forceinline__ int sc_load1_nw(const int* p) {   // no embedded wait
    int v;
    asm volatile("global_load_dword %0, %1, off sc0 sc1" : "=v"(v) : "v"(p));
    return v;
}
__device__ __forceinline__ void sc_store_int(int* p, int v) {
    asm volatile("global_store_dword %0, %1, off sc0 sc1" :: "v"(p), "v"(v) : "memory");
}
__device__ __forceinline__ void sc_store_short(unsigned short* p, unsigned v) {
    asm volatile("global_store_short %0, %1, off sc0 sc1" :: "v"(p), "v"(v) : "memory");
}
__device__ __forceinline__ i32x2 g_load8(const void* p) {    // plain cached, no wait
    i32x2 v;
    asm volatile("global_load_dwordx2 %0, %1, off" : "=v"(v) : "v"(p));
    return v;
}
__device__ __forceinline__ void wait_vm0() {
    asm volatile("s_waitcnt vmcnt(0)" ::: "memory");
}
__device__ __forceinline__ void wait_vm16() {
    asm volatile("s_waitcnt vmcnt(16)" ::: "memory");
}

__device__ __forceinline__ void gload_lds16(const void* g, void* l) {
    __builtin_amdgcn_global_load_lds(
        (const __attribute__((address_space(1))) void*)g,
        (__attribute__((address_space(3))) void*)l, 16, 0, 0);
}

__device__ __forceinline__ float sigmoidf_(float x) { return 1.f / (1.f + expf(-x)); }

// ---------------- fp32 -> bf16 conversion ----------------
__global__ __launch_bounds__(256) void f2b_kernel(
    const float* __restrict__ in, unsigned short* __restrict__ out, int n4)
{
    const int stride = gridDim.x * 256;
    for (int i = blockIdx.x * 256 + threadIdx.x; i < n4; i += stride) {
        const float4 v = reinterpret_cast<const float4*>(in)[i];
        u16x4 o = { f2bf(v.x), f2bf(v.y), f2bf(v.z), f2bf(v.w) };
        reinterpret_cast<u16x4*>(out)[i] = o;
    }
}

// ---------------- embedding gathers (emit bf16) ----------------
__global__ __launch_bounds__(64) void embed_src_kernel(
    const int* __restrict__ toks, const float* __restrict__ emb,
    unsigned short* __restrict__ out)
{
    const int i = blockIdx.x;
    const int tok = toks[i];
    const float4 v = reinterpret_cast<const float4*>(emb + (size_t)tok * EMBD)[threadIdx.x];
    u16x4 o = { f2bf(v.x), f2bf(v.y), f2bf(v.z), f2bf(v.w) };
    reinterpret_cast<u16x4*>(out + (size_t)i * EMBD)[threadIdx.x] = o;
}

__global__ __launch_bounds__(64) void embed_dec_kernel(
    const int* __restrict__ sent, const int* __restrict__ targ,
    const float* __restrict__ emb, unsigned short* __restrict__ out)
{
    const int i = blockIdx.x;
    const int t = i >> 6, b = i & 63;
    const int tok = (t == 0) ? sent[(S_LEN - 1) * BSZ + b] : targ[(t - 1) * BSZ + b];
    const float4 v = reinterpret_cast<const float4*>(emb + (size_t)tok * EMBD)[threadIdx.x];
    u16x4 o = { f2bf(v.x), f2bf(v.y), f2bf(v.z), f2bf(v.w) };
    reinterpret_cast<u16x4*>(out + (size_t)i * EMBD)[threadIdx.x] = o;
}

// ---------------- bf16 MFMA GEMM:  C = A[M,K] * B[N,K]^T + b1 (+ b2) ----------------
// tmode 0: C fp32 row-major (M,N). tmode 1: C bf16 as (M/64, N, 64) = (T,4H,B).
__global__ __launch_bounds__(256) void gemm_bf16_kernel(
    const unsigned short* __restrict__ A, const unsigned short* __restrict__ B,
    const float* __restrict__ b1, const float* __restrict__ b2,
    void* __restrict__ Cv, int M, int N, int K, int nTN, int tmode)
{
    __shared__ __align__(16) unsigned short As[128 * 64];
    __shared__ __align__(16) unsigned short Bs[128 * 64];

    const int tid  = threadIdx.x;
    const int lane = tid & 63;
    const int wv   = tid >> 6;
    const int wm   = wv >> 1, wn = wv & 1;

    const int nwg = gridDim.x;
    const int q = nwg >> 3, r = nwg & 7;
    const int xcd = blockIdx.x & 7, io = blockIdx.x >> 3;
    const int wg = (xcd < r ? xcd * (q + 1) : r * (q + 1) + (xcd - r) * q) + io;
    const int bm = (wg / nTN) * 128;
    const int bn = (wg % nTN) * 128;

    f32x4 acc[4][4];
#pragma unroll
    for (int i = 0; i < 4; ++i)
#pragma unroll
        for (int j = 0; j < 4; ++j) acc[i][j] = (f32x4)0.f;

    const int lin_base = wv * 1024 + lane * 16;

    for (int k0 = 0; k0 < K; k0 += 64) {
        __syncthreads();
#pragma unroll
        for (int qc = 0; qc < 4; ++qc) {
            const int lin = qc * 4096 + lin_base;
            const int row = lin >> 7;
            const int c   = (lin >> 4) & 7;
            const int sc  = c ^ (row & 7);
            const size_t gofs  = (size_t)(bm + row) * K + k0 + sc * 8;
            const size_t gofsB = (size_t)(bn + row) * K + k0 + sc * 8;
            char* ldst  = (char*)As + qc * 4096 + wv * 1024;
            char* ldstB = (char*)Bs + qc * 4096 + wv * 1024;
            gload_lds16(A + gofs, ldst);
            gload_lds16(B + gofsB, ldstB);
        }
        asm volatile("s_waitcnt vmcnt(0)" ::: "memory");
        __syncthreads();
#pragma unroll
        for (int ks = 0; ks < 2; ++ks) {
            bf16x8 af[4], bfv[4];
            const int ca = ks * 4 + (lane >> 4);
#pragma unroll
            for (int f = 0; f < 4; ++f) {
                const int ra = wm * 64 + f * 16 + (lane & 15);
                af[f] = __builtin_bit_cast(bf16x8,
                    *(const s16x8*)((const char*)As + ra * 128 + ((ca ^ (ra & 7)) << 4)));
                const int rb = wn * 64 + f * 16 + (lane & 15);
                bfv[f] = __builtin_bit_cast(bf16x8,
                    *(const s16x8*)((const char*)Bs + rb * 128 + ((ca ^ (rb & 7)) << 4)));
            }
#pragma unroll
            for (int i = 0; i < 4; ++i)
#pragma unroll
                for (int j = 0; j < 4; ++j)
                    acc[i][j] = __builtin_amdgcn_mfma_f32_16x16x32_bf16(
                        af[i], bfv[j], acc[i][j], 0, 0, 0);
        }
    }

    const int col0 = bn + wn * 64 + (lane & 15);
    if (tmode == 0) {
        float* C = (float*)Cv;
        const int row0 = bm + wm * 64 + ((lane >> 4) << 2);
#pragma unroll
        for (int i = 0; i < 4; ++i) {
#pragma unroll
            for (int j = 0; j < 4; ++j) {
                const int col = col0 + j * 16;
                float bias = b1[col];
                if (b2) bias += b2[col];
#pragma unroll
                for (int rg = 0; rg < 4; ++rg)
                    C[(size_t)(row0 + i * 16 + rg) * N + col] = acc[i][j][rg] + bias;
            }
        }
    } else {
        unsigned short* C = (unsigned short*)Cv;
        const int tblk = (bm >> 6) + wm;
        const int rb = (lane >> 4) << 2;
#pragma unroll
        for (int i = 0; i < 4; ++i) {
#pragma unroll
            for (int j = 0; j < 4; ++j) {
                const int col = col0 + j * 16;
                float bias = b1[col];
                if (b2) bias += b2[col];
                u16x4 o = { f2bf(acc[i][j][0] + bias), f2bf(acc[i][j][1] + bias),
                            f2bf(acc[i][j][2] + bias), f2bf(acc[i][j][3] + bias) };
                *reinterpret_cast<u16x4*>(&C[((size_t)tblk * N + col) * 64 + rb + i * 16]) = o;
            }
        }
    }
}

// ---------------- persistent MFMA LSTM scan: one chain per WAVE ----------------
// Block = 4 cells (m0 = blk*4 within dir); 4 waves = 4 independent 16-batch chains.
// No __syncthreads in the step loop: each wave polls its own (dir, quarter) flag
// domain, stages its private 16xH h tile, MFMAs, combines gates via shfl_xor,
// keeps c-state in registers, stores h, drains ITS OWN vmcnt, then flags.
// xw: bf16 (T,4H,B). hist: (T,B,1024) bf16 (h history AND y output).
// Flags: bar + ((dirblk*4 + quarter)*16) ints, 64B apart. Grid = ndir*(H_T/4) = 256.
template<int H_T>
__global__ __launch_bounds__(256, 1) void lstm_wave_scan(
    const unsigned short* __restrict__ xw0, const unsigned short* __restrict__ xw1,
    const float* __restrict__ Whh0, const float* __restrict__ Whh1,
    const unsigned short* __restrict__ h0b, const float* __restrict__ c0,
    unsigned short* __restrict__ hist,
    unsigned short* __restrict__ hsb, float* __restrict__ csd,
    int T, int ndir, int rev_mask, int* bar)
{
    constexpr int NCB = H_T / 4;         // blocks per dir (128 enc / 256 dec)
    constexpr int NF  = NCB / 64;        // poll loads per lane (2 / 4)
    constexpr int NCH = H_T / 512;       // K chunks (1 enc / 2 dec)
    constexpr int CH  = H_T / 8;         // 16B chunks per Whh row

    __shared__ __align__(16) unsigned short w_lds[16 * H_T];      // 16/32 KB
    __shared__ __align__(16) unsigned short h_lds[4][16 * 512];   // 4 x 16 KB

    const int tid  = threadIdx.x;
    const int lane = tid & 63;
    const int w    = tid >> 6;           // quarter / chain
    const int n    = lane & 15;          // gate*4 + cell
    const int kg   = lane >> 4;
    const int g    = n >> 2;
    const int cl   = n & 3;
    const int dir  = blockIdx.x / NCB;
    const int blk  = blockIdx.x - dir * NCB;
    const int m0   = blk * 4;
    const int rev  = (rev_mask >> dir) & 1;
    const unsigned short* xw = dir ? xw1 : xw0;
    const float* Whh = dir ? Whh1 : Whh0;
    const int dcol = dir * H_T;
    const int b0   = w * 16;             // chain's batch base

    int* myflag = bar + (((dir * NCB + blk) << 2) + w) * 16;
    const int* pf[NF];
#pragma unroll
    for (int j = 0; j < NF; ++j)
        pf[j] = bar + (((dir * NCB + (lane + j * 64)) << 2) + w) * 16;

    // ---- stage Whh (16 rows = 4 gates x 4 cells, full K) into swizzled LDS ----
    for (int idx = tid; idx < 16 * CH; idx += 256) {
        const int r_ = idx / CH, cc = idx - r_ * CH;
        const float* wp = Whh + (size_t)((r_ >> 2) * H_T + m0 + (r_ & 3)) * H_T + cc * 8;
        const float4 lo = *reinterpret_cast<const float4*>(wp);
        const float4 hi = *reinterpret_cast<const float4*>(wp + 4);
        s16x8 rr;
        rr[0] = (short)f2bf(lo.x); rr[1] = (short)f2bf(lo.y);
        rr[2] = (short)f2bf(lo.z); rr[3] = (short)f2bf(lo.w);
        rr[4] = (short)f2bf(hi.x); rr[5] = (short)f2bf(hi.y);
        rr[6] = (short)f2bf(hi.z); rr[7] = (short)f2bf(hi.w);
        *(s16x8*)((char*)w_lds + r_ * (2 * H_T) + (((cc & ~7) | ((cc ^ r_) & 7)) << 4)) = rr;
    }

    // g0-lane state: 4 batches (kg*4+rg) of cell n
    float cst[4] = {0.f, 0.f, 0.f, 0.f};
    if (g == 0 && c0) {
#pragma unroll
        for (int rg = 0; rg < 4; ++rg)
            cst[rg] = c0[(size_t)(b0 + kg * 4 + rg) * HSTR + dcol + m0 + n];
    }
    float hnv[4] = {0.f, 0.f, 0.f, 0.f};

    // xw prefetch: one 8B load per lane = 4 batches of (gate g, cell cl)
    const unsigned short* xbase =
        xw + ((size_t)(g * H_T + m0 + cl)) * 64 + b0 + kg * 4;
    i32x2 xg;
    auto issue_xg = [&](int ttn) {
        xg = g_load8(xbase + (size_t)ttn * (4 * H_T) * 64);
    };
    issue_xg(rev ? (T - 1) : 0);
    __syncthreads();                     // w_lds ready (only sync outside step loop)

    for (int s = 0; s < T; ++s) {
        const int tt = rev ? (T - 1 - s) : s;

        // ---- wave-private poll of this chain's producers ----
        if (s > 0) {
            for (;;) {
                int f[NF];
#pragma unroll
                for (int j = 0; j < NF; ++j) f[j] = sc_load1_nw(pf[j]);
                wait_vm0();
                bool ok = true;
#pragma unroll
                for (int j = 0; j < NF; ++j) ok &= (f[j] >= s);
                if (__all(ok)) break;
                __builtin_amdgcn_s_sleep(4);
            }
        }

        const unsigned short* hb;
        size_t tofs;
        if (s == 0) { hb = h0b; tofs = 0; }
        else {
            const int tp = rev ? (tt + 1) : (tt - 1);
            hb = hist; tofs = (size_t)tp * (64 * 1024);
        }

        f32x4 acc = {0.f, 0.f, 0.f, 0.f};
        if (hb) {
            const unsigned short* src = hb + tofs + dcol;
            char* hl = (char*)&h_lds[w][0];
            f4_t bufA[16];
#pragma unroll
            for (int jj = 0; jj < 16; ++jj)
                bufA[jj] = sc_load4(src + (size_t)(b0 + jj) * 1024 + lane * 8);
            f4_t bufB[16];
            if constexpr (NCH == 2) {
#pragma unroll
                for (int jj = 0; jj < 16; ++jj)
                    bufB[jj] = sc_load4(src + (size_t)(b0 + jj) * 1024 + 512 + lane * 8);
                wait_vm16();
            } else {
                wait_vm0();
            }
#pragma unroll
            for (int jj = 0; jj < 16; ++jj)
                *(f4_t*)(hl + jj * 1024 + (((lane & 56) | ((lane ^ jj) & 7)) << 4)) = bufA[jj];
#pragma unroll
            for (int ks = 0; ks < 16; ++ks) {
                const int ca = ks * 4 + kg;
                const bf16x8 a = __builtin_bit_cast(bf16x8,
                    *(const s16x8*)(hl + n * 1024 + (((ca & 56) | ((ca ^ n) & 7)) << 4)));
                const bf16x8 b = __builtin_bit_cast(bf16x8,
                    *(const s16x8*)((const char*)w_lds + n * (2 * H_T)
                                    + (((ca & ~7) | ((ca ^ n) & 7)) << 4)));
                acc = __builtin_amdgcn_mfma_f32_16x16x32_bf16(a, b, acc, 0, 0, 0);
            }
            if constexpr (NCH == 2) {
                wait_vm0();
#pragma unroll
                for (int jj = 0; jj < 16; ++jj)
                    *(f4_t*)(hl + jj * 1024 + (((lane & 56) | ((lane ^ jj) & 7)) << 4)) = bufB[jj];
#pragma unroll
                for (int ks = 0; ks < 16; ++ks) {
                    const int ca = ks * 4 + kg;
                    const int gc = 64 + ca;
                    const bf16x8 a = __builtin_bit_cast(bf16x8,
                        *(const s16x8*)(hl + n * 1024 + (((ca & 56) | ((ca ^ n) & 7)) << 4)));
                    const bf16x8 b = __builtin_bit_cast(bf16x8,
                        *(const s16x8*)((const char*)w_lds + n * (2 * H_T)
                                        + (((gc & ~7) | ((gc ^ n) & 7)) << 4)));
                    acc = __builtin_amdgcn_mfma_f32_16x16x32_bf16(a, b, acc, 0, 0, 0);
                }
            }
        }

        // xw (prefetched last step) — tie to a vmcnt wait
        asm volatile("s_waitcnt vmcnt(0)" : "+v"(xg) :: "memory");
        const unsigned x0u = (unsigned)xg[0], x1u = (unsigned)xg[1];
        const float xwf[4] = { bf2f(x0u & 0xffffu), bf2f(x0u >> 16),
                               bf2f(x1u & 0xffffu), bf2f(x1u >> 16) };

        // branchless activation: g==2 -> tanh = 2*sigmoid(2x)-1
        const bool is2 = (g == 2);
        const float kk = is2 ? 2.f : 1.f;
        const float sub = is2 ? 1.f : 0.f;
        float act[4];
#pragma unroll
        for (int rg = 0; rg < 4; ++rg) {
            const float p = acc[rg] + xwf[rg];
            act[rg] = kk * sigmoidf_(kk * p) - sub;
        }
        // combine gates onto g0 lanes (intra-wave): x8=tanh g, x4a=sigma_f, x4b=sigma_o
        float x8[4], x4a[4], x4b[4];
#pragma unroll
        for (int rg = 0; rg < 4; ++rg) {
            x8[rg]  = __shfl_xor(act[rg], 8);
            x4a[rg] = __shfl_xor(act[rg], 4);
            x4b[rg] = __shfl_xor(x8[rg], 4);
        }
        if (g == 0) {
#pragma unroll
            for (int rg = 0; rg < 4; ++rg) {
                cst[rg] = x4a[rg] * cst[rg] + act[rg] * x8[rg];
                hnv[rg] = x4b[rg] * tanhf(cst[rg]);
                sc_store_short(hist + (size_t)tt * (64 * 1024)
                               + (size_t)(b0 + kg * 4 + rg) * 1024
                               + dcol + m0 + n, (unsigned)f2bf(hnv[rg]));
            }
        }
        wait_vm0();                       // wave-private drain: only OUR h stores
        if (s + 1 < T) {
            if (lane == 0) sc_store_int(myflag, s + 1);
            issue_xg(rev ? (T - 2 - s) : (s + 1));
        }
    }

    if (hsb && g == 0) {
#pragma unroll
        for (int rg = 0; rg < 4; ++rg) {
            const int b_ = b0 + kg * 4 + rg;
            hsb[(size_t)b_ * 1024 + dcol + m0 + n] = f2bf(hnv[rg]);
            csd[(size_t)b_ * HSTR + dcol + m0 + n] = cst[rg];
        }
    }
}

// ---------------- in-place row log-softmax (float4) ----------------
__global__ __launch_bounds__(256) void logsoftmax_kernel(float* __restrict__ x, int n4)
{
    const int tid = threadIdx.x;
    float4* p = reinterpret_cast<float4*>(x + (size_t)blockIdx.x * (n4 * 4));
    float m = -3.0e38f, s = 0.f;
    for (int cc = tid; cc < n4; cc += 256) {
        const float4 v = p[cc];
        const float vv[4] = { v.x, v.y, v.z, v.w };
#pragma unroll
        for (int e = 0; e < 4; ++e) {
            const float z = vv[e];
            if (z > m) { s = s * expf(m - z) + 1.f; m = z; }
            else       { s += expf(z - m); }
        }
    }
    __shared__ float ms[256], ss[256];
    ms[tid] = m; ss[tid] = s;
    __syncthreads();
    for (int off = 128; off > 0; off >>= 1) {
        if (tid < off) {
            const float m2 = ms[tid + off], s2 = ss[tid + off];
            const float m1 = ms[tid],       s1 = ss[tid];
            const float M = fmaxf(m1, m2);
            ss[tid] = s1 * expf(m1 - M) + s2 * expf(m2 - M);
            ms[tid] = M;
        }
        __syncthreads();
    }
    const float ML = ms[0] + logf(ss[0]);
    for (int cc = tid; cc < n4; cc += 256) {
        float4 v = p[cc];
        v.x -= ML; v.y -= ML; v.z -= ML; v.w -= ML;
        p[cc] = v;
    }
}

// ---------------- host-side orchestration ----------------
extern "C" void kernel_launch(void* const* d_in, const int* in_sizes, int n_in,
                              void* d_out, int out_size, void* d_ws, size_t ws_size,
                              hipStream_t stream)
{
    const int*   sent  = (const int*)d_in[0];
    const int*   targ  = (const int*)d_in[1];
    const float* emb   = (const float*)d_in[2];
    const float* e0Wih = (const float*)d_in[3];
    const float* e0Whh = (const float*)d_in[4];
    const float* e0bih = (const float*)d_in[5];
    const float* e0bhh = (const float*)d_in[6];
    const float* e1Wih = (const float*)d_in[7];
    const float* e1Whh = (const float*)d_in[8];
    const float* e1bih = (const float*)d_in[9];
    const float* e1bhh = (const float*)d_in[10];
    const float* d0Wih = (const float*)d_in[11];
    const float* d0Whh = (const float*)d_in[12];
    const float* d0bih = (const float*)d_in[13];
    const float* d0bhh = (const float*)d_in[14];
    const float* d1Wih = (const float*)d_in[15];
    const float* d1Whh = (const float*)d_in[16];
    const float* d1bih = (const float*)d_in[17];
    const float* d1bhh = (const float*)d_in[18];
    const float* Wout  = (const float*)d_in[19];
    const float* bout  = (const float*)d_in[20];

    float* ws  = (float*)d_ws;
    float* cs  = ws + WS_CS;
    int*   bar = (int*)(ws + WS_BAR);
    unsigned short* ub    = (unsigned short*)(ws + WS_BF);
    unsigned short* x0b   = ub + U_X0B;
    unsigned short* h_e0  = ub + U_HE0;
    unsigned short* h_e1  = ub + U_HE1;
    unsigned short* h_d0  = ub + U_HD0;
    unsigned short* h_d1  = ub + U_HD1;
    unsigned short* hsb   = ub + U_HSB;
    unsigned short* e0Wb  = ub + U_E0W;
    unsigned short* e1Wb  = ub + U_E1W;
    unsigned short* d0Wb  = ub + U_D0W;
    unsigned short* d1Wb  = ub + U_D1W;
    unsigned short* xwA   = ub + U_XWA;
    unsigned short* xwB   = ub + U_XWB;
    unsigned short* Woutb = ub + U_WOUT;
    float* out = (float*)d_out;

    hipMemsetAsync(bar, 0, 4 * 16384 * sizeof(int), stream);

    // ---- weight conversions (fp32 -> bf16) ----
    f2b_kernel<<<256, 256, 0, stream>>>(e0Wih, e0Wb, 1048576 / 4);
    f2b_kernel<<<512, 256, 0, stream>>>(e1Wih, e1Wb, 4194304 / 4);
    f2b_kernel<<<256, 256, 0, stream>>>(d0Wih, d0Wb, 1048576 / 4);
    f2b_kernel<<<512, 256, 0, stream>>>(d1Wih, d1Wb, 4194304 / 4);
    f2b_kernel<<<2048, 256, 0, stream>>>(Wout, Woutb, (VOC_ * DHID_) / 4);

    // ---- encoder layer 0 ----
    embed_src_kernel<<<S_LEN * BSZ, 64, 0, stream>>>(sent, emb, x0b);
    gemm_bf16_kernel<<<64 * 16, 256, 0, stream>>>(x0b, e0Wb, e0bih, e0bhh, xwA,
                                                  S_LEN * BSZ, 2048, EMBD, 16, 1);
    gemm_bf16_kernel<<<64 * 16, 256, 0, stream>>>(x0b, e0Wb + 2048ull * 256,
                                                  e0bih + 2048, e0bhh + 2048, xwB,
                                                  S_LEN * BSZ, 2048, EMBD, 16, 1);
    lstm_wave_scan<512><<<256, 256, 0, stream>>>(xwA, xwB, e0Whh, e0Whh + 2048ull * 512,
                                                 nullptr, nullptr, h_e0,
                                                 hsb, cs, S_LEN, 2, 2, bar);
    // ---- encoder layer 1 (final states only) ----
    gemm_bf16_kernel<<<64 * 16, 256, 0, stream>>>(h_e0, e1Wb, e1bih, e1bhh, xwA,
                                                  S_LEN * BSZ, 2048, 2 * HID_, 16, 1);
    gemm_bf16_kernel<<<64 * 16, 256, 0, stream>>>(h_e0, e1Wb + 2048ull * 1024,
                                                  e1bih + 2048, e1bhh + 2048, xwB,
                                                  S_LEN * BSZ, 2048, 2 * HID_, 16, 1);
    lstm_wave_scan<512><<<256, 256, 0, stream>>>(xwA, xwB, e1Whh, e1Whh + 2048ull * 512,
                                                 nullptr, nullptr, h_e1,
                                                 hsb + 65536, cs + 65536,
                                                 S_LEN, 2, 2, bar + 16384);
    // ---- decoder layer 0 ----
    embed_dec_kernel<<<T_LEN * BSZ, 64, 0, stream>>>(sent, targ, emb, x0b);
    gemm_bf16_kernel<<<32 * 32, 256, 0, stream>>>(x0b, d0Wb, d0bih, d0bhh, xwA,
                                                  T_LEN * BSZ, 4 * DHID_, EMBD, 32, 1);
    lstm_wave_scan<1024><<<256, 256, 0, stream>>>(xwA, nullptr, d0Whh, nullptr,
                                                  hsb, cs, h_d0,
                                                  nullptr, nullptr, T_LEN, 1, 0,
                                                  bar + 2 * 16384);
    // ---- decoder layer 1 ----
    gemm_bf16_kernel<<<32 * 32, 256, 0, stream>>>(h_d0, d1Wb, d1bih, d1bhh, xwB,
                                                  T_LEN * BSZ, 4 * DHID_, DHID_, 32, 1);
    lstm_wave_scan<1024><<<256, 256, 0, stream>>>(xwB, nullptr, d1Whh, nullptr,
                                                  hsb + 65536, cs + 65536, h_d1,
                                                  nullptr, nullptr, T_LEN, 1, 0,
                                                  bar + 3 * 16384);
    // ---- vocab projection + log-softmax ----
    gemm_bf16_kernel<<<32 * 250, 256, 0, stream>>>(h_d1, Woutb, bout, nullptr, out,
                                                   T_LEN * BSZ, VOC_, DHID_, 250, 0);
    logsoftmax_kernel<<<T_LEN * BSZ, 256, 0, stream>>>(out, VOC_ / 4);
}

// Round 11
// 2959.097 us; speedup vs baseline: 1.3745x; 1.3745x over previous
//
#include <hip/hip_runtime.h>

#define S_LEN 128
#define T_LEN 64
#define BSZ   64
#define EMBD  256
#define HID_  512
#define DHID_ 1024
#define VOC_  32000
#define HSTR  1024

typedef float  f4_t  __attribute__((ext_vector_type(4)));
typedef float  f32x4 __attribute__((ext_vector_type(4)));
typedef short  s16x8 __attribute__((ext_vector_type(8)));
typedef __bf16 bf16x8 __attribute__((ext_vector_type(8)));
typedef unsigned short u16x4 __attribute__((ext_vector_type(4)));
typedef int    i32x2 __attribute__((ext_vector_type(2)));

// ---------------- workspace layout ----------------
// float offsets:
#define WS_XWA  0ull                       // 16,777,216 fl
#define WS_XWB  (WS_XWA + 16777216ull)     // 16,777,216 fl
#define WS_CS   (WS_XWB + 16777216ull)     // 131,072 fl
#define WS_BAR  (WS_CS  + 131072ull)       // 32,768 ints (4 regions x 8192)
#define WS_BF   (WS_BAR + 32768ull)
// ushort offsets within bf16 region:
#define U_X0B   0ull
#define U_HE0   (U_X0B + 2097152ull)
#define U_HE1   (U_HE0 + 8388608ull)
#define U_HD0   (U_HE1 + 8388608ull)
#define U_HD1   (U_HD0 + 4194304ull)
#define U_HSB   (U_HD1 + 4194304ull)
#define U_E0W   (U_HSB + 131072ull)
#define U_E1W   (U_E0W + 1048576ull)
#define U_D0W   (U_E1W + 4194304ull)
#define U_D1W   (U_D0W + 1048576ull)

__device__ __forceinline__ unsigned short f2bf(float x) {
    unsigned u = __builtin_bit_cast(unsigned, x);
    return (unsigned short)((u + 0x7fffu + ((u >> 16) & 1u)) >> 16);
}

// ---------------- coherent (LLC-scope) memory helpers ----------------
__device__ __forceinline__ f4_t sc_load4(const void* p) {
    f4_t v;
    asm volatile("global_load_dwordx4 %0, %1, off sc0 sc1" : "=v"(v) : "v"(p));
    return v;                               // NOT ready until a vmcnt wait
}
__device__ __forceinline__ int sc_load1(const int* p) {
    int v;
    asm volatile("global_load_dword %0, %1, off sc0 sc1\n\ts_waitcnt vmcnt(0)"
                 : "=v"(v) : "v"(p) : "memory");
    return v;
}
__device__ __forceinline__ void sc_store_int(int* p, int v) {
    asm volatile("global_store_dword %0, %1, off sc0 sc1" :: "v"(p), "v"(v) : "memory");
}
__device__ __forceinline__ void sc_store8(void* p, i32x2 v) {
    asm volatile("global_store_dwordx2 %0, %1, off sc0 sc1" :: "v"(p), "v"(v) : "memory");
}
__device__ __forceinline__ float g_load1(const float* p) {   // plain cached load, no wait
    float v;
    asm volatile("global_load_dword %0, %1, off" : "=v"(v) : "v"(p));
    return v;
}
__device__ __forceinline__ void wait_vm0() {
    asm volatile("s_waitcnt vmcnt(0)" ::: "memory");
}
__device__ __forceinline__ void wait_vm8() {
    asm volatile("s_waitcnt vmcnt(8)" ::: "memory");
}

__device__ __forceinline__ void gload_lds16(const void* g, void* l) {
    __builtin_amdgcn_global_load_lds(
        (const __attribute__((address_space(1))) void*)g,
        (__attribute__((address_space(3))) void*)l, 16, 0, 0);
}

__device__ __forceinline__ float sigmoidf_(float x) { return 1.f / (1.f + expf(-x)); }

// ---------------- fp32 -> bf16 conversion ----------------
__global__ __launch_bounds__(256) void f2b_kernel(
    const float* __restrict__ in, unsigned short* __restrict__ out, int n4)
{
    const int stride = gridDim.x * 256;
    for (int i = blockIdx.x * 256 + threadIdx.x; i < n4; i += stride) {
        const float4 v = reinterpret_cast<const float4*>(in)[i];
        u16x4 o = { f2bf(v.x), f2bf(v.y), f2bf(v.z), f2bf(v.w) };
        reinterpret_cast<u16x4*>(out)[i] = o;
    }
}

// ---------------- embedding gathers (emit bf16) ----------------
__global__ __launch_bounds__(64) void embed_src_kernel(
    const int* __restrict__ toks, const float* __restrict__ emb,
    unsigned short* __restrict__ out)
{
    const int i = blockIdx.x;
    const int tok = toks[i];
    const float4 v = reinterpret_cast<const float4*>(emb + (size_t)tok * EMBD)[threadIdx.x];
    u16x4 o = { f2bf(v.x), f2bf(v.y), f2bf(v.z), f2bf(v.w) };
    reinterpret_cast<u16x4*>(out + (size_t)i * EMBD)[threadIdx.x] = o;
}

__global__ __launch_bounds__(64) void embed_dec_kernel(
    const int* __restrict__ sent, const int* __restrict__ targ,
    const float* __restrict__ emb, unsigned short* __restrict__ out)
{
    const int i = blockIdx.x;
    const int t = i >> 6, b = i & 63;
    const int tok = (t == 0) ? sent[(S_LEN - 1) * BSZ + b] : targ[(t - 1) * BSZ + b];
    const float4 v = reinterpret_cast<const float4*>(emb + (size_t)tok * EMBD)[threadIdx.x];
    u16x4 o = { f2bf(v.x), f2bf(v.y), f2bf(v.z), f2bf(v.w) };
    reinterpret_cast<u16x4*>(out + (size_t)i * EMBD)[threadIdx.x] = o;
}

// ---------------- bf16 MFMA GEMM:  C = A[M,K] * B[N,K]^T + b1 (+ b2) ----------------
// tmode 0: C row-major (M,N). tmode 1: C as (M/64, N, 64) i.e. (T,4H,B) for the scans.
__global__ __launch_bounds__(256) void gemm_bf16_kernel(
    const unsigned short* __restrict__ A, const unsigned short* __restrict__ B,
    const float* __restrict__ b1, const float* __restrict__ b2,
    float* __restrict__ C, int M, int N, int K, int nTN, int tmode)
{
    __shared__ __align__(16) unsigned short As[128 * 64];
    __shared__ __align__(16) unsigned short Bs[128 * 64];

    const int tid  = threadIdx.x;
    const int lane = tid & 63;
    const int wv   = tid >> 6;
    const int wm   = wv >> 1, wn = wv & 1;

    const int nwg = gridDim.x;
    const int q = nwg >> 3, r = nwg & 7;
    const int xcd = blockIdx.x & 7, io = blockIdx.x >> 3;
    const int wg = (xcd < r ? xcd * (q + 1) : r * (q + 1) + (xcd - r) * q) + io;
    const int bm = (wg / nTN) * 128;
    const int bn = (wg % nTN) * 128;

    f32x4 acc[4][4];
#pragma unroll
    for (int i = 0; i < 4; ++i)
#pragma unroll
        for (int j = 0; j < 4; ++j) acc[i][j] = (f32x4)0.f;

    const int lin_base = wv * 1024 + lane * 16;

    for (int k0 = 0; k0 < K; k0 += 64) {
        __syncthreads();
#pragma unroll
        for (int qc = 0; qc < 4; ++qc) {
            const int lin = qc * 4096 + lin_base;
            const int row = lin >> 7;
            const int c   = (lin >> 4) & 7;
            const int sc  = c ^ (row & 7);
            const size_t gofs  = (size_t)(bm + row) * K + k0 + sc * 8;
            const size_t gofsB = (size_t)(bn + row) * K + k0 + sc * 8;
            char* ldst  = (char*)As + qc * 4096 + wv * 1024;
            char* ldstB = (char*)Bs + qc * 4096 + wv * 1024;
            gload_lds16(A + gofs, ldst);
            gload_lds16(B + gofsB, ldstB);
        }
        asm volatile("s_waitcnt vmcnt(0)" ::: "memory");
        __syncthreads();
#pragma unroll
        for (int ks = 0; ks < 2; ++ks) {
            bf16x8 af[4], bfv[4];
            const int ca = ks * 4 + (lane >> 4);
#pragma unroll
            for (int f = 0; f < 4; ++f) {
                const int ra = wm * 64 + f * 16 + (lane & 15);
                af[f] = __builtin_bit_cast(bf16x8,
                    *(const s16x8*)((const char*)As + ra * 128 + ((ca ^ (ra & 7)) << 4)));
                const int rb = wn * 64 + f * 16 + (lane & 15);
                bfv[f] = __builtin_bit_cast(bf16x8,
                    *(const s16x8*)((const char*)Bs + rb * 128 + ((ca ^ (rb & 7)) << 4)));
            }
#pragma unroll
            for (int i = 0; i < 4; ++i)
#pragma unroll
                for (int j = 0; j < 4; ++j)
                    acc[i][j] = __builtin_amdgcn_mfma_f32_16x16x32_bf16(
                        af[i], bfv[j], acc[i][j], 0, 0, 0);
        }
    }

    const int col0 = bn + wn * 64 + (lane & 15);
    if (tmode == 0) {
        const int row0 = bm + wm * 64 + ((lane >> 4) << 2);
#pragma unroll
        for (int i = 0; i < 4; ++i) {
#pragma unroll
            for (int j = 0; j < 4; ++j) {
                const int col = col0 + j * 16;
                float bias = b1[col];
                if (b2) bias += b2[col];
#pragma unroll
                for (int rg = 0; rg < 4; ++rg)
                    C[(size_t)(row0 + i * 16 + rg) * N + col] = acc[i][j][rg] + bias;
            }
        }
    } else {
        // (row>>6, col, row&63); acc's 4 regs are 4 consecutive rows -> one float4
        const int tblk = (bm >> 6) + wm;
        const int rb = (lane >> 4) << 2;
#pragma unroll
        for (int i = 0; i < 4; ++i) {
#pragma unroll
            for (int j = 0; j < 4; ++j) {
                const int col = col0 + j * 16;
                float bias = b1[col];
                if (b2) bias += b2[col];
                float4 v = { acc[i][j][0] + bias, acc[i][j][1] + bias,
                             acc[i][j][2] + bias, acc[i][j][3] + bias };
                *reinterpret_cast<float4*>(&C[((size_t)tblk * N + col) * 64 + rb + i * 16]) = v;
            }
        }
    }
}

// ---------------- persistent MFMA LSTM scan, single-hop flag sync (R5-exact) ----------------
// Grid 256x256. hist: (T,B,1024) bf16. xw layout: (T, 4*H_T, B) per dir (transposed).
// Flags: bar + blockIdx.x*32; producer stores s+1 after its h stores drained;
// every block polls all bpd producer flags of its dir directly (no gen hop).
template<int H_T>
__global__ __launch_bounds__(256, 1) void lstm_mfma_scan(
    const float* __restrict__ xw0, const float* __restrict__ xw1,
    const float* __restrict__ Whh0, const float* __restrict__ Whh1,
    const unsigned short* __restrict__ h0b, const float* __restrict__ c0,
    unsigned short* __restrict__ hist,
    unsigned short* __restrict__ hsb, float* __restrict__ csd,
    int T, int ndir, int rev_mask, int* bar)
{
    constexpr int KST = H_T / 32;
    constexpr int CH  = H_T / 8;
    constexpr int NB  = (64 * CH) / 2048;

    __shared__ __align__(16) unsigned short h_lds[64 * H_T];
    __shared__ float pre[64][17];
    __shared__ __align__(8) unsigned short hpack[64][4];

    const int tid  = threadIdx.x;
    const int lane = tid & 63;
    const int w    = tid >> 6;
    const int bpd  = (ndir == 2) ? 128 : 256;
    const int dir  = blockIdx.x / bpd;
    const int blk  = blockIdx.x - dir * bpd;
    const int m0   = blk * 4;
    const int rev  = (rev_mask >> dir) & 1;
    const float* xw  = dir ? xw1  : xw0;
    const float* Whh = dir ? Whh1 : Whh0;
    const int dcol = dir * H_T;
    const int b = tid & 63;
    const int j = tid >> 6;

    int* myflag = bar + blockIdx.x * 32;
    const int* pollflag = bar + (dir * bpd + (tid < bpd ? tid : 0)) * 32;
    const bool polls = (tid < bpd);

    // ---- B-fragments: Whh rows in registers, bf16 ----
    const int n  = lane & 15;           // (gate,cell) = (n>>2, n&3)
    const int kg = lane >> 4;
    const int wr = (n >> 2) * H_T + m0 + (n & 3);
    s16x8 wfr[KST];
#pragma unroll
    for (int ks = 0; ks < KST; ++ks) {
        const float* wp = Whh + (size_t)wr * H_T + ks * 32 + kg * 8;
        const float4 lo = *reinterpret_cast<const float4*>(wp);
        const float4 hi = *reinterpret_cast<const float4*>(wp + 4);
        s16x8 rr;
        rr[0] = (short)f2bf(lo.x); rr[1] = (short)f2bf(lo.y);
        rr[2] = (short)f2bf(lo.z); rr[3] = (short)f2bf(lo.w);
        rr[4] = (short)f2bf(hi.x); rr[5] = (short)f2bf(hi.y);
        rr[6] = (short)f2bf(hi.z); rr[7] = (short)f2bf(hi.w);
        wfr[ks] = rr;
    }

    float c  = c0 ? c0[(size_t)b * HSTR + dcol + m0 + j] : 0.f;
    float hn = 0.f;
    const int rA  = w * 16 + n;
    const int rAx = rA & 7;

    for (int s = 0; s < T; ++s) {
        const int tt = rev ? (T - 1 - s) : s;

        // coalesced xw gate loads: layout (tt, 4H, b)
        const float* xb = xw + ((size_t)tt * (4 * H_T) + m0 + j) * 64 + b;
        float xg0 = g_load1(xb);
        float xg1 = g_load1(xb + (size_t)H_T * 64);
        float xg2 = g_load1(xb + (size_t)2 * H_T * 64);
        float xg3 = g_load1(xb + (size_t)3 * H_T * 64);

        // single-hop: wait for all producers of step s-1
        if (s > 0) {
            int ok = polls ? 0 : 1;
            for (;;) {
                if (!ok) ok = (sc_load1(pollflag) >= s) ? 1 : 0;
                if (__syncthreads_and(ok)) break;
            }
        }

        const unsigned short* hb;
        size_t tofs;
        if (s == 0) { hb = h0b; tofs = 0; }
        else {
            const int tp = rev ? (tt + 1) : (tt - 1);
            hb = hist; tofs = (size_t)tp * (64 * 1024);
        }

        float p0 = 0.f, p1 = 0.f, p2 = 0.f, p3 = 0.f;
        if (hb) {
            // ---- stage h tile: sc_load4 -> XOR-swizzled LDS, 2-deep counted pipeline ----
            f4_t bufA[8], bufB[8];
            auto issue = [&](f4_t (&bf)[8], int bt) {
#pragma unroll
                for (int jj = 0; jj < 8; ++jj) {
                    const int idx = (bt * 8 + jj) * 256 + tid;
                    const int rr_ = idx / CH, cc_ = idx % CH;
                    bf[jj] = sc_load4(hb + tofs + (size_t)rr_ * 1024 + dcol + cc_ * 8);
                }
            };
            auto writeb = [&](const f4_t (&bf)[8], int bt) {
#pragma unroll
                for (int jj = 0; jj < 8; ++jj) {
                    const int idx = (bt * 8 + jj) * 256 + tid;
                    const int rr_ = idx / CH, cc_ = idx % CH;
                    const int off = rr_ * (2 * H_T) + ((cc_ ^ (rr_ & 7)) << 4);
                    *(f4_t*)((char*)h_lds + off) = bf[jj];
                }
            };
            issue(bufA, 0);
            if (NB > 1) issue(bufB, 1);
#pragma unroll
            for (int bt = 0; bt < NB; ++bt) {
                if (bt + 1 < NB) wait_vm8(); else wait_vm0();
                if (bt & 1) writeb(bufB, bt); else writeb(bufA, bt);
                if (bt + 2 < NB) { if (bt & 1) issue(bufB, bt + 2); else issue(bufA, bt + 2); }
            }
            __syncthreads();

            // ---- MFMA: D[batch][n] += h[batch][k] * W[wr(n)][k] ----
            f32x4 acc = {0.f, 0.f, 0.f, 0.f};
#pragma unroll
            for (int ks = 0; ks < KST; ++ks) {
                const int cc_ = ks * 4 + kg;
                const int off = rA * (2 * H_T) + ((cc_ ^ rAx) << 4);
                const bf16x8 a = __builtin_bit_cast(bf16x8,
                    *(const s16x8*)((const char*)h_lds + off));
                acc = __builtin_amdgcn_mfma_f32_16x16x32_bf16(
                    a, __builtin_bit_cast(bf16x8, wfr[ks]), acc, 0, 0, 0);
            }
            // ---- exchange D -> (b, gate) layout ----
            __syncthreads();
#pragma unroll
            for (int rg = 0; rg < 4; ++rg)
                pre[w * 16 + kg * 4 + rg][n] = acc[rg];
            __syncthreads();
            p0 = pre[b][0 + j]; p1 = pre[b][4 + j];
            p2 = pre[b][8 + j]; p3 = pre[b][12 + j];
        }

        asm volatile("s_waitcnt vmcnt(0)"
                     : "+v"(xg0), "+v"(xg1), "+v"(xg2), "+v"(xg3) :: "memory");

        const float ig = sigmoidf_(p0 + xg0);
        const float fg = sigmoidf_(p1 + xg1);
        const float gg = tanhf(p2 + xg2);
        const float og = sigmoidf_(p3 + xg3);
        c  = fg * c + ig * gg;
        hn = og * tanhf(c);

        // pack 4 cells x 64 batches in LDS -> 64 coherent 8B stores
        hpack[b][j] = f2bf(hn);
        __syncthreads();
        if (tid < 64) {
            const i32x2 v2 = *reinterpret_cast<const i32x2*>(&hpack[tid][0]);
            sc_store8(hist + (size_t)tt * (64 * 1024) + (size_t)tid * 1024 + dcol + m0, v2);
        }
        wait_vm0();
        __syncthreads();          // ALL threads' stores drained before flag
        if (s + 1 < T && tid == 0) sc_store_int(myflag, s + 1);
    }

    if (hsb) hsb[(size_t)b * 1024 + dcol + m0 + j] = f2bf(hn);
    if (csd) csd[(size_t)b * HSTR + dcol + m0 + j] = c;
}

// ---------------- single-pass row log-softmax: row staged in LDS ----------------
// One block per row (32000 floats = 125 KB LDS). Read row once (online max/sum +
// stash in LDS), reduce, then normalize from LDS. Global traffic: 1 read + 1 write.
__global__ __launch_bounds__(256) void logsoftmax_kernel(float* __restrict__ x, int n4)
{
    __shared__ __align__(16) float row[VOC_];   // 125 KB
    __shared__ float ms[256], ss[256];
    const int tid = threadIdx.x;
    float4* p = reinterpret_cast<float4*>(x + (size_t)blockIdx.x * (n4 * 4));
    float m = -3.0e38f, s = 0.f;
    for (int cc = tid; cc < n4; cc += 256) {
        const float4 v = p[cc];
        *reinterpret_cast<float4*>(&row[cc * 4]) = v;
        const float vv[4] = { v.x, v.y, v.z, v.w };
#pragma unroll
        for (int e = 0; e < 4; ++e) {
            const float z = vv[e];
            if (z > m) { s = s * expf(m - z) + 1.f; m = z; }
            else       { s += expf(z - m); }
        }
    }
    ms[tid] = m; ss[tid] = s;
    __syncthreads();
    for (int off = 128; off > 0; off >>= 1) {
        if (tid < off) {
            const float m2 = ms[tid + off], s2 = ss[tid + off];
            const float m1 = ms[tid],       s1 = ss[tid];
            const float M = fmaxf(m1, m2);
            ss[tid] = s1 * expf(m1 - M) + s2 * expf(m2 - M);
            ms[tid] = M;
        }
        __syncthreads();
    }
    const float ML = ms[0] + logf(ss[0]);
    for (int cc = tid; cc < n4; cc += 256) {
        float4 v = *reinterpret_cast<const float4*>(&row[cc * 4]);
        v.x -= ML; v.y -= ML; v.z -= ML; v.w -= ML;
        p[cc] = v;
    }
}

// ---------------- host-side orchestration ----------------
extern "C" void kernel_launch(void* const* d_in, const int* in_sizes, int n_in,
                              void* d_out, int out_size, void* d_ws, size_t ws_size,
                              hipStream_t stream)
{
    const int*   sent  = (const int*)d_in[0];
    const int*   targ  = (const int*)d_in[1];
    const float* emb   = (const float*)d_in[2];
    const float* e0Wih = (const float*)d_in[3];
    const float* e0Whh = (const float*)d_in[4];
    const float* e0bih = (const float*)d_in[5];
    const float* e0bhh = (const float*)d_in[6];
    const float* e1Wih = (const float*)d_in[7];
    const float* e1Whh = (const float*)d_in[8];
    const float* e1bih = (const float*)d_in[9];
    const float* e1bhh = (const float*)d_in[10];
    const float* d0Wih = (const float*)d_in[11];
    const float* d0Whh = (const float*)d_in[12];
    const float* d0bih = (const float*)d_in[13];
    const float* d0bhh = (const float*)d_in[14];
    const float* d1Wih = (const float*)d_in[15];
    const float* d1Whh = (const float*)d_in[16];
    const float* d1bih = (const float*)d_in[17];
    const float* d1bhh = (const float*)d_in[18];
    const float* Wout  = (const float*)d_in[19];
    const float* bout  = (const float*)d_in[20];

    float* ws  = (float*)d_ws;
    float* xwA = ws + WS_XWA;
    float* xwB = ws + WS_XWB;
    float* cs  = ws + WS_CS;
    int*   bar = (int*)(ws + WS_BAR);
    unsigned short* ub    = (unsigned short*)(ws + WS_BF);
    unsigned short* x0b   = ub + U_X0B;
    unsigned short* h_e0  = ub + U_HE0;
    unsigned short* h_e1  = ub + U_HE1;
    unsigned short* h_d0  = ub + U_HD0;
    unsigned short* h_d1  = ub + U_HD1;
    unsigned short* hsb   = ub + U_HSB;
    unsigned short* e0Wb  = ub + U_E0W;
    unsigned short* e1Wb  = ub + U_E1W;
    unsigned short* d0Wb  = ub + U_D0W;
    unsigned short* d1Wb  = ub + U_D1W;
    unsigned short* Woutb = (unsigned short*)xwA;   // reused after dec0 scan
    float* out = (float*)d_out;

    hipMemsetAsync(bar, 0, 4 * 8192 * sizeof(int), stream);

    // ---- weight conversions (fp32 -> bf16) ----
    f2b_kernel<<<256, 256, 0, stream>>>(e0Wih, e0Wb, 1048576 / 4);
    f2b_kernel<<<512, 256, 0, stream>>>(e1Wih, e1Wb, 4194304 / 4);
    f2b_kernel<<<256, 256, 0, stream>>>(d0Wih, d0Wb, 1048576 / 4);
    f2b_kernel<<<512, 256, 0, stream>>>(d1Wih, d1Wb, 4194304 / 4);

    // ---- encoder layer 0 ----
    embed_src_kernel<<<S_LEN * BSZ, 64, 0, stream>>>(sent, emb, x0b);
    gemm_bf16_kernel<<<64 * 16, 256, 0, stream>>>(x0b, e0Wb, e0bih, e0bhh, xwA,
                                                  S_LEN * BSZ, 2048, EMBD, 16, 1);
    gemm_bf16_kernel<<<64 * 16, 256, 0, stream>>>(x0b, e0Wb + 2048ull * 256,
                                                  e0bih + 2048, e0bhh + 2048, xwB,
                                                  S_LEN * BSZ, 2048, EMBD, 16, 1);
    lstm_mfma_scan<512><<<256, 256, 0, stream>>>(xwA, xwB, e0Whh, e0Whh + 2048ull * 512,
                                                 nullptr, nullptr, h_e0,
                                                 hsb, cs, S_LEN, 2, 2, bar);
    // ---- encoder layer 1 (final states only) ----
    gemm_bf16_kernel<<<64 * 16, 256, 0, stream>>>(h_e0, e1Wb, e1bih, e1bhh, xwA,
                                                  S_LEN * BSZ, 2048, 2 * HID_, 16, 1);
    gemm_bf16_kernel<<<64 * 16, 256, 0, stream>>>(h_e0, e1Wb + 2048ull * 1024,
                                                  e1bih + 2048, e1bhh + 2048, xwB,
                                                  S_LEN * BSZ, 2048, 2 * HID_, 16, 1);
    lstm_mfma_scan<512><<<256, 256, 0, stream>>>(xwA, xwB, e1Whh, e1Whh + 2048ull * 512,
                                                 nullptr, nullptr, h_e1,
                                                 hsb + 65536, cs + 65536,
                                                 S_LEN, 2, 2, bar + 8192);
    // ---- decoder layer 0 ----
    embed_dec_kernel<<<T_LEN * BSZ, 64, 0, stream>>>(sent, targ, emb, x0b);
    gemm_bf16_kernel<<<32 * 32, 256, 0, stream>>>(x0b, d0Wb, d0bih, d0bhh, xwA,
                                                  T_LEN * BSZ, 4 * DHID_, EMBD, 32, 1);
    lstm_mfma_scan<1024><<<256, 256, 0, stream>>>(xwA, nullptr, d0Whh, nullptr,
                                                  hsb, cs, h_d0,
                                                  nullptr, nullptr, T_LEN, 1, 0,
                                                  bar + 2 * 8192);
    // ---- Wout -> bf16 (xwA region free after dec0 scan; stream-ordered) ----
    f2b_kernel<<<2048, 256, 0, stream>>>(Wout, Woutb, (VOC_ * DHID_) / 4);
    // ---- decoder layer 1 ----
    gemm_bf16_kernel<<<32 * 32, 256, 0, stream>>>(h_d0, d1Wb, d1bih, d1bhh, xwB,
                                                  T_LEN * BSZ, 4 * DHID_, DHID_, 32, 1);
    lstm_mfma_scan<1024><<<256, 256, 0, stream>>>(xwB, nullptr, d1Whh, nullptr,
                                                  hsb + 65536, cs + 65536, h_d1,
                                                  nullptr, nullptr, T_LEN, 1, 0,
                                                  bar + 3 * 8192);
    // ---- vocab projection + log-softmax ----
    gemm_bf16_kernel<<<32 * 250, 256, 0, stream>>>(h_d1, Woutb, bout, nullptr, out,
                                                   T_LEN * BSZ, VOC_, DHID_, 250, 0);
    logsoftmax_kernel<<<T_LEN * BSZ, 256, 0, stream>>>(out, VOC_ / 4);
}

// Round 12
// 2679.366 us; speedup vs baseline: 1.5179x; 1.1044x over previous
//
#include <hip/hip_runtime.h>

#define S_LEN 128
#define T_LEN 64
#define BSZ   64
#define EMBD  256
#define HID_  512
#define DHID_ 1024
#define VOC_  32000
#define HSTR  1024

typedef float  f4_t  __attribute__((ext_vector_type(4)));
typedef float  f32x4 __attribute__((ext_vector_type(4)));
typedef short  s16x8 __attribute__((ext_vector_type(8)));
typedef __bf16 bf16x8 __attribute__((ext_vector_type(8)));
typedef unsigned short u16x4 __attribute__((ext_vector_type(4)));
typedef int    i32x2 __attribute__((ext_vector_type(2)));

// ---------------- workspace layout ----------------
// float offsets:
#define WS_XWA  0ull                       // 16,777,216 fl (enc xw spans XWA+XWB contiguously)
#define WS_XWB  (WS_XWA + 16777216ull)     // 16,777,216 fl
#define WS_CS   (WS_XWB + 16777216ull)     // 131,072 fl (c-state; later ML row constants)
#define WS_BAR  (WS_CS  + 131072ull)       // 32,768 ints (4 regions x 8192)
#define WS_BF   (WS_BAR + 32768ull)
// ushort offsets within bf16 region:
#define U_X0B   0ull
#define U_HE0   (U_X0B + 2097152ull)
#define U_HE1   (U_HE0 + 8388608ull)
#define U_HD0   (U_HE1 + 8388608ull)
#define U_HD1   (U_HD0 + 4194304ull)
#define U_HSB   (U_HD1 + 4194304ull)
#define U_E0W   (U_HSB + 131072ull)
#define U_E1W   (U_E0W + 1048576ull)
#define U_D0W   (U_E1W + 4194304ull)
#define U_D1W   (U_D0W + 1048576ull)

__device__ __forceinline__ unsigned short f2bf(float x) {
    unsigned u = __builtin_bit_cast(unsigned, x);
    return (unsigned short)((u + 0x7fffu + ((u >> 16) & 1u)) >> 16);
}

// ---------------- coherent (LLC-scope) memory helpers ----------------
__device__ __forceinline__ f4_t sc_load4(const void* p) {
    f4_t v;
    asm volatile("global_load_dwordx4 %0, %1, off sc0 sc1" : "=v"(v) : "v"(p));
    return v;                               // NOT ready until a vmcnt wait
}
__device__ __forceinline__ int sc_load1(const int* p) {
    int v;
    asm volatile("global_load_dword %0, %1, off sc0 sc1\n\ts_waitcnt vmcnt(0)"
                 : "=v"(v) : "v"(p) : "memory");
    return v;
}
__device__ __forceinline__ void sc_store_int(int* p, int v) {
    asm volatile("global_store_dword %0, %1, off sc0 sc1" :: "v"(p), "v"(v) : "memory");
}
__device__ __forceinline__ void sc_store8(void* p, i32x2 v) {
    asm volatile("global_store_dwordx2 %0, %1, off sc0 sc1" :: "v"(p), "v"(v) : "memory");
}
__device__ __forceinline__ float g_load1(const float* p) {   // plain cached load, no wait
    float v;
    asm volatile("global_load_dword %0, %1, off" : "=v"(v) : "v"(p));
    return v;
}
__device__ __forceinline__ void wait_vm0() {
    asm volatile("s_waitcnt vmcnt(0)" ::: "memory");
}
__device__ __forceinline__ void wait_vm8() {
    asm volatile("s_waitcnt vmcnt(8)" ::: "memory");
}

__device__ __forceinline__ void gload_lds16(const void* g, void* l) {
    __builtin_amdgcn_global_load_lds(
        (const __attribute__((address_space(1))) void*)g,
        (__attribute__((address_space(3))) void*)l, 16, 0, 0);
}

__device__ __forceinline__ float sigmoidf_(float x) { return 1.f / (1.f + expf(-x)); }

// ---------------- fp32 -> bf16 conversion ----------------
__global__ __launch_bounds__(256) void f2b_kernel(
    const float* __restrict__ in, unsigned short* __restrict__ out, int n4)
{
    const int stride = gridDim.x * 256;
    for (int i = blockIdx.x * 256 + threadIdx.x; i < n4; i += stride) {
        const float4 v = reinterpret_cast<const float4*>(in)[i];
        u16x4 o = { f2bf(v.x), f2bf(v.y), f2bf(v.z), f2bf(v.w) };
        reinterpret_cast<u16x4*>(out)[i] = o;
    }
}

// ---------------- embedding gathers (emit bf16) ----------------
__global__ __launch_bounds__(64) void embed_src_kernel(
    const int* __restrict__ toks, const float* __restrict__ emb,
    unsigned short* __restrict__ out)
{
    const int i = blockIdx.x;
    const int tok = toks[i];
    const float4 v = reinterpret_cast<const float4*>(emb + (size_t)tok * EMBD)[threadIdx.x];
    u16x4 o = { f2bf(v.x), f2bf(v.y), f2bf(v.z), f2bf(v.w) };
    reinterpret_cast<u16x4*>(out + (size_t)i * EMBD)[threadIdx.x] = o;
}

__global__ __launch_bounds__(64) void embed_dec_kernel(
    const int* __restrict__ sent, const int* __restrict__ targ,
    const float* __restrict__ emb, unsigned short* __restrict__ out)
{
    const int i = blockIdx.x;
    const int t = i >> 6, b = i & 63;
    const int tok = (t == 0) ? sent[(S_LEN - 1) * BSZ + b] : targ[(t - 1) * BSZ + b];
    const float4 v = reinterpret_cast<const float4*>(emb + (size_t)tok * EMBD)[threadIdx.x];
    u16x4 o = { f2bf(v.x), f2bf(v.y), f2bf(v.z), f2bf(v.w) };
    reinterpret_cast<u16x4*>(out + (size_t)i * EMBD)[threadIdx.x] = o;
}

// ---------------- bf16 MFMA GEMM:  C = A[M,K] * B[N,K]^T + b1 (+ b2) ----------------
// tmode 0: C fp32 row-major (M,N). tmode 1: C fp32 as (M/64, N, 64) = (T,N,B).
// part (tmode 0 only, nullable): per-(row, col-tile) log-softmax partials
// (max, sumexp) written as part[(row*nTN + bn/128)*2 + {0,1}].
__global__ __launch_bounds__(256) void gemm_bf16_kernel(
    const unsigned short* __restrict__ A, const unsigned short* __restrict__ B,
    const float* __restrict__ b1, const float* __restrict__ b2,
    float* __restrict__ C, int M, int N, int K, int nTN, int tmode,
    float* __restrict__ part)
{
    __shared__ __align__(16) unsigned short As[128 * 64];
    __shared__ __align__(16) unsigned short Bs[128 * 64];
    __shared__ float prt[2][128][2];

    const int tid  = threadIdx.x;
    const int lane = tid & 63;
    const int wv   = tid >> 6;
    const int wm   = wv >> 1, wn = wv & 1;

    const int nwg = gridDim.x;
    const int q = nwg >> 3, r = nwg & 7;
    const int xcd = blockIdx.x & 7, io = blockIdx.x >> 3;
    const int wg = (xcd < r ? xcd * (q + 1) : r * (q + 1) + (xcd - r) * q) + io;
    const int bm = (wg / nTN) * 128;
    const int bn = (wg % nTN) * 128;

    f32x4 acc[4][4];
#pragma unroll
    for (int i = 0; i < 4; ++i)
#pragma unroll
        for (int j = 0; j < 4; ++j) acc[i][j] = (f32x4)0.f;

    const int lin_base = wv * 1024 + lane * 16;

    for (int k0 = 0; k0 < K; k0 += 64) {
        __syncthreads();
#pragma unroll
        for (int qc = 0; qc < 4; ++qc) {
            const int lin = qc * 4096 + lin_base;
            const int row = lin >> 7;
            const int c   = (lin >> 4) & 7;
            const int sc  = c ^ (row & 7);
            const size_t gofs  = (size_t)(bm + row) * K + k0 + sc * 8;
            const size_t gofsB = (size_t)(bn + row) * K + k0 + sc * 8;
            char* ldst  = (char*)As + qc * 4096 + wv * 1024;
            char* ldstB = (char*)Bs + qc * 4096 + wv * 1024;
            gload_lds16(A + gofs, ldst);
            gload_lds16(B + gofsB, ldstB);
        }
        asm volatile("s_waitcnt vmcnt(0)" ::: "memory");
        __syncthreads();
#pragma unroll
        for (int ks = 0; ks < 2; ++ks) {
            bf16x8 af[4], bfv[4];
            const int ca = ks * 4 + (lane >> 4);
#pragma unroll
            for (int f = 0; f < 4; ++f) {
                const int ra = wm * 64 + f * 16 + (lane & 15);
                af[f] = __builtin_bit_cast(bf16x8,
                    *(const s16x8*)((const char*)As + ra * 128 + ((ca ^ (ra & 7)) << 4)));
                const int rb = wn * 64 + f * 16 + (lane & 15);
                bfv[f] = __builtin_bit_cast(bf16x8,
                    *(const s16x8*)((const char*)Bs + rb * 128 + ((ca ^ (rb & 7)) << 4)));
            }
#pragma unroll
            for (int i = 0; i < 4; ++i)
#pragma unroll
                for (int j = 0; j < 4; ++j)
                    acc[i][j] = __builtin_amdgcn_mfma_f32_16x16x32_bf16(
                        af[i], bfv[j], acc[i][j], 0, 0, 0);
        }
    }

    const int col0 = bn + wn * 64 + (lane & 15);
    if (tmode == 0) {
        const int row0 = bm + wm * 64 + ((lane >> 4) << 2);
        float bs[4];
#pragma unroll
        for (int j = 0; j < 4; ++j) {
            const int col = col0 + j * 16;
            bs[j] = b1[col];
            if (b2) bs[j] += b2[col];
        }
#pragma unroll
        for (int i = 0; i < 4; ++i)
#pragma unroll
            for (int j = 0; j < 4; ++j)
#pragma unroll
                for (int rg = 0; rg < 4; ++rg)
                    C[(size_t)(row0 + i * 16 + rg) * N + col0 + j * 16] = acc[i][j][rg] + bs[j];

        if (part) {
            // per-row partial max over this wave's 64 cols
            float pm[4][4], ps[4][4];
#pragma unroll
            for (int i = 0; i < 4; ++i)
#pragma unroll
                for (int rg = 0; rg < 4; ++rg) {
                    float m = acc[i][0][rg] + bs[0];
                    m = fmaxf(m, acc[i][1][rg] + bs[1]);
                    m = fmaxf(m, acc[i][2][rg] + bs[2]);
                    m = fmaxf(m, acc[i][3][rg] + bs[3]);
                    pm[i][rg] = m;
                }
#pragma unroll
            for (int mask = 1; mask <= 8; mask <<= 1)
#pragma unroll
                for (int i = 0; i < 4; ++i)
#pragma unroll
                    for (int rg = 0; rg < 4; ++rg)
                        pm[i][rg] = fmaxf(pm[i][rg], __shfl_xor(pm[i][rg], mask));
#pragma unroll
            for (int i = 0; i < 4; ++i)
#pragma unroll
                for (int rg = 0; rg < 4; ++rg) {
                    float s = 0.f;
#pragma unroll
                    for (int j = 0; j < 4; ++j)
                        s += expf(acc[i][j][rg] + bs[j] - pm[i][rg]);
                    ps[i][rg] = s;
                }
#pragma unroll
            for (int mask = 1; mask <= 8; mask <<= 1)
#pragma unroll
                for (int i = 0; i < 4; ++i)
#pragma unroll
                    for (int rg = 0; rg < 4; ++rg)
                        ps[i][rg] += __shfl_xor(ps[i][rg], mask);
            if ((lane & 15) == 0) {
#pragma unroll
                for (int i = 0; i < 4; ++i)
#pragma unroll
                    for (int rg = 0; rg < 4; ++rg) {
                        const int r64 = ((lane >> 4) << 2) + i * 16 + rg;
                        prt[wn][wm * 64 + r64][0] = pm[i][rg];
                        prt[wn][wm * 64 + r64][1] = ps[i][rg];
                    }
            }
            __syncthreads();
            if (tid < 128) {
                const float m0_ = prt[0][tid][0], s0_ = prt[0][tid][1];
                const float m1_ = prt[1][tid][0], s1_ = prt[1][tid][1];
                const float Mx = fmaxf(m0_, m1_);
                const float Sx = s0_ * expf(m0_ - Mx) + s1_ * expf(m1_ - Mx);
                const size_t o = ((size_t)(bm + tid) * nTN + (bn >> 7)) * 2;
                part[o] = Mx; part[o + 1] = Sx;
            }
        }
    } else {
        const int tblk = (bm >> 6) + wm;
        const int rb = (lane >> 4) << 2;
#pragma unroll
        for (int i = 0; i < 4; ++i) {
#pragma unroll
            for (int j = 0; j < 4; ++j) {
                const int col = col0 + j * 16;
                float bias = b1[col];
                if (b2) bias += b2[col];
                float4 v = { acc[i][j][0] + bias, acc[i][j][1] + bias,
                             acc[i][j][2] + bias, acc[i][j][3] + bias };
                *reinterpret_cast<float4*>(&C[((size_t)tblk * N + col) * 64 + rb + i * 16]) = v;
            }
        }
    }
}

// ---------------- persistent MFMA LSTM scan, single-hop flag sync (R5 structure) ----------------
// Grid 256x256. hist: (T,B,1024) bf16. xw: fp32 (T, 4096, B) — t-stride 4096 cols always
// (enc: both dirs merged, dir1 at col 2048; dec: 4H=4096).
template<int H_T>
__global__ __launch_bounds__(256, 1) void lstm_mfma_scan(
    const float* __restrict__ xw0, const float* __restrict__ xw1,
    const float* __restrict__ Whh0, const float* __restrict__ Whh1,
    const unsigned short* __restrict__ h0b, const float* __restrict__ c0,
    unsigned short* __restrict__ hist,
    unsigned short* __restrict__ hsb, float* __restrict__ csd,
    int T, int ndir, int rev_mask, int* bar)
{
    constexpr int KST = H_T / 32;
    constexpr int CH  = H_T / 8;
    constexpr int NB  = (64 * CH) / 2048;

    __shared__ __align__(16) unsigned short h_lds[64 * H_T];
    __shared__ float pre[64][17];
    __shared__ __align__(8) unsigned short hpack[64][4];

    const int tid  = threadIdx.x;
    const int lane = tid & 63;
    const int w    = tid >> 6;
    const int bpd  = (ndir == 2) ? 128 : 256;
    const int dir  = blockIdx.x / bpd;
    const int blk  = blockIdx.x - dir * bpd;
    const int m0   = blk * 4;
    const int rev  = (rev_mask >> dir) & 1;
    const float* xw  = dir ? xw1  : xw0;
    const float* Whh = dir ? Whh1 : Whh0;
    const int dcol = dir * H_T;
    const int b = tid & 63;
    const int j = tid >> 6;

    int* myflag = bar + blockIdx.x * 32;
    const int* pollflag = bar + (dir * bpd + (tid < bpd ? tid : 0)) * 32;
    const bool polls = (tid < bpd);

    // ---- B-fragments: Whh rows in registers, bf16 ----
    const int n  = lane & 15;           // (gate,cell) = (n>>2, n&3)
    const int kg = lane >> 4;
    const int wr = (n >> 2) * H_T + m0 + (n & 3);
    s16x8 wfr[KST];
#pragma unroll
    for (int ks = 0; ks < KST; ++ks) {
        const float* wp = Whh + (size_t)wr * H_T + ks * 32 + kg * 8;
        const float4 lo = *reinterpret_cast<const float4*>(wp);
        const float4 hi = *reinterpret_cast<const float4*>(wp + 4);
        s16x8 rr;
        rr[0] = (short)f2bf(lo.x); rr[1] = (short)f2bf(lo.y);
        rr[2] = (short)f2bf(lo.z); rr[3] = (short)f2bf(lo.w);
        rr[4] = (short)f2bf(hi.x); rr[5] = (short)f2bf(hi.y);
        rr[6] = (short)f2bf(hi.z); rr[7] = (short)f2bf(hi.w);
        wfr[ks] = rr;
    }

    float c  = c0 ? c0[(size_t)b * HSTR + dcol + m0 + j] : 0.f;
    float hn = 0.f;
    const int rA  = w * 16 + n;
    const int rAx = rA & 7;

    for (int s = 0; s < T; ++s) {
        const int tt = rev ? (T - 1 - s) : s;

        // coalesced xw gate loads: layout (tt, 4096, b)
        const float* xb = xw + ((size_t)tt * 4096 + m0 + j) * 64 + b;
        float xg0 = g_load1(xb);
        float xg1 = g_load1(xb + (size_t)H_T * 64);
        float xg2 = g_load1(xb + (size_t)2 * H_T * 64);
        float xg3 = g_load1(xb + (size_t)3 * H_T * 64);

        // single-hop: wait for all producers of step s-1
        if (s > 0) {
            int ok = polls ? 0 : 1;
            for (;;) {
                if (!ok) ok = (sc_load1(pollflag) >= s) ? 1 : 0;
                if (__syncthreads_and(ok)) break;
            }
        }

        const unsigned short* hb;
        size_t tofs;
        if (s == 0) { hb = h0b; tofs = 0; }
        else {
            const int tp = rev ? (tt + 1) : (tt - 1);
            hb = hist; tofs = (size_t)tp * (64 * 1024);
        }

        float p0 = 0.f, p1 = 0.f, p2 = 0.f, p3 = 0.f;
        if (hb) {
            // ---- stage h tile: sc_load4 -> XOR-swizzled LDS, 2-deep counted pipeline ----
            f4_t bufA[8], bufB[8];
            auto issue = [&](f4_t (&bf)[8], int bt) {
#pragma unroll
                for (int jj = 0; jj < 8; ++jj) {
                    const int idx = (bt * 8 + jj) * 256 + tid;
                    const int rr_ = idx / CH, cc_ = idx % CH;
                    bf[jj] = sc_load4(hb + tofs + (size_t)rr_ * 1024 + dcol + cc_ * 8);
                }
            };
            auto writeb = [&](const f4_t (&bf)[8], int bt) {
#pragma unroll
                for (int jj = 0; jj < 8; ++jj) {
                    const int idx = (bt * 8 + jj) * 256 + tid;
                    const int rr_ = idx / CH, cc_ = idx % CH;
                    const int off = rr_ * (2 * H_T) + ((cc_ ^ (rr_ & 7)) << 4);
                    *(f4_t*)((char*)h_lds + off) = bf[jj];
                }
            };
            issue(bufA, 0);
            if (NB > 1) issue(bufB, 1);
#pragma unroll
            for (int bt = 0; bt < NB; ++bt) {
                if (bt + 1 < NB) wait_vm8(); else wait_vm0();
                if (bt & 1) writeb(bufB, bt); else writeb(bufA, bt);
                if (bt + 2 < NB) { if (bt & 1) issue(bufB, bt + 2); else issue(bufA, bt + 2); }
            }
            __syncthreads();

            // ---- MFMA: D[batch][n] += h[batch][k] * W[wr(n)][k] ----
            f32x4 acc = {0.f, 0.f, 0.f, 0.f};
#pragma unroll
            for (int ks = 0; ks < KST; ++ks) {
                const int cc_ = ks * 4 + kg;
                const int off = rA * (2 * H_T) + ((cc_ ^ rAx) << 4);
                const bf16x8 a = __builtin_bit_cast(bf16x8,
                    *(const s16x8*)((const char*)h_lds + off));
                acc = __builtin_amdgcn_mfma_f32_16x16x32_bf16(
                    a, __builtin_bit_cast(bf16x8, wfr[ks]), acc, 0, 0, 0);
            }
            // ---- exchange D -> (b, gate) layout ----
            __syncthreads();
#pragma unroll
            for (int rg = 0; rg < 4; ++rg)
                pre[w * 16 + kg * 4 + rg][n] = acc[rg];
            __syncthreads();
            p0 = pre[b][0 + j]; p1 = pre[b][4 + j];
            p2 = pre[b][8 + j]; p3 = pre[b][12 + j];
        }

        asm volatile("s_waitcnt vmcnt(0)"
                     : "+v"(xg0), "+v"(xg1), "+v"(xg2), "+v"(xg3) :: "memory");

        const float ig = sigmoidf_(p0 + xg0);
        const float fg = sigmoidf_(p1 + xg1);
        const float gg = tanhf(p2 + xg2);
        const float og = sigmoidf_(p3 + xg3);
        c  = fg * c + ig * gg;
        hn = og * tanhf(c);

        // pack 4 cells x 64 batches in LDS -> 64 coherent 8B stores
        hpack[b][j] = f2bf(hn);
        __syncthreads();
        if (tid < 64) {
            const i32x2 v2 = *reinterpret_cast<const i32x2*>(&hpack[tid][0]);
            sc_store8(hist + (size_t)tt * (64 * 1024) + (size_t)tid * 1024 + dcol + m0, v2);
        }
        wait_vm0();
        __syncthreads();          // ALL threads' stores drained before flag
        if (s + 1 < T && tid == 0) sc_store_int(myflag, s + 1);
    }

    if (hsb) hsb[(size_t)b * 1024 + dcol + m0 + j] = f2bf(hn);
    if (csd) csd[(size_t)b * HSTR + dcol + m0 + j] = c;
}

// ---------------- log-softmax: merge per-tile partials -> per-row M+logS ----------------
__global__ __launch_bounds__(256) void lsm_merge_kernel(
    const float* __restrict__ part, float* __restrict__ ml, int nt)
{
    __shared__ float ms[256], ss[256];
    const int tid = threadIdx.x;
    float m = -3.0e38f, s = 0.f;
    for (int t = tid; t < nt; t += 256) {
        const float mo = part[((size_t)blockIdx.x * nt + t) * 2];
        const float so = part[((size_t)blockIdx.x * nt + t) * 2 + 1];
        const float M = fmaxf(m, mo);
        s = s * expf(m - M) + so * expf(mo - M);
        m = M;
    }
    ms[tid] = m; ss[tid] = s;
    __syncthreads();
    for (int off = 128; off > 0; off >>= 1) {
        if (tid < off) {
            const float m2 = ms[tid + off], s2 = ss[tid + off];
            const float m1 = ms[tid],       s1 = ss[tid];
            const float M = fmaxf(m1, m2);
            ss[tid] = s1 * expf(m1 - M) + s2 * expf(m2 - M);
            ms[tid] = M;
        }
        __syncthreads();
    }
    if (tid == 0) ml[blockIdx.x] = ms[0] + logf(ss[0]);
}

// ---------------- log-softmax: normalize (single read+write pass) ----------------
__global__ __launch_bounds__(256) void lsm_norm_kernel(
    float* __restrict__ x, const float* __restrict__ ml, int n4)
{
    const float ML = ml[blockIdx.x];
    float4* p = reinterpret_cast<float4*>(x + (size_t)blockIdx.x * (n4 * 4));
    for (int cc = threadIdx.x; cc < n4; cc += 256) {
        float4 v = p[cc];
        v.x -= ML; v.y -= ML; v.z -= ML; v.w -= ML;
        p[cc] = v;
    }
}

// ---------------- host-side orchestration ----------------
extern "C" void kernel_launch(void* const* d_in, const int* in_sizes, int n_in,
                              void* d_out, int out_size, void* d_ws, size_t ws_size,
                              hipStream_t stream)
{
    const int*   sent  = (const int*)d_in[0];
    const int*   targ  = (const int*)d_in[1];
    const float* emb   = (const float*)d_in[2];
    const float* e0Wih = (const float*)d_in[3];
    const float* e0Whh = (const float*)d_in[4];
    const float* e0bih = (const float*)d_in[5];
    const float* e0bhh = (const float*)d_in[6];
    const float* e1Wih = (const float*)d_in[7];
    const float* e1Whh = (const float*)d_in[8];
    const float* e1bih = (const float*)d_in[9];
    const float* e1bhh = (const float*)d_in[10];
    const float* d0Wih = (const float*)d_in[11];
    const float* d0Whh = (const float*)d_in[12];
    const float* d0bih = (const float*)d_in[13];
    const float* d0bhh = (const float*)d_in[14];
    const float* d1Wih = (const float*)d_in[15];
    const float* d1Whh = (const float*)d_in[16];
    const float* d1bih = (const float*)d_in[17];
    const float* d1bhh = (const float*)d_in[18];
    const float* Wout  = (const float*)d_in[19];
    const float* bout  = (const float*)d_in[20];

    float* ws  = (float*)d_ws;
    float* xwA = ws + WS_XWA;               // enc xw spans XWA+XWB (33.5M fl)
    float* xwB = ws + WS_XWB;               // dec1 xw; later softmax partials
    float* cs  = ws + WS_CS;                // c-state; later ML row constants
    int*   bar = (int*)(ws + WS_BAR);
    unsigned short* ub    = (unsigned short*)(ws + WS_BF);
    unsigned short* x0b   = ub + U_X0B;
    unsigned short* h_e0  = ub + U_HE0;
    unsigned short* h_e1  = ub + U_HE1;
    unsigned short* h_d0  = ub + U_HD0;
    unsigned short* h_d1  = ub + U_HD1;
    unsigned short* hsb   = ub + U_HSB;
    unsigned short* e0Wb  = ub + U_E0W;
    unsigned short* e1Wb  = ub + U_E1W;
    unsigned short* d0Wb  = ub + U_D0W;
    unsigned short* d1Wb  = ub + U_D1W;
    unsigned short* Woutb = (unsigned short*)xwA;   // reused after dec0 scan
    float* out = (float*)d_out;
    float* ml  = cs;                        // 4096 row constants (c-state dead by then)

    hipMemsetAsync(bar, 0, 4 * 8192 * sizeof(int), stream);

    // ---- weight conversions (fp32 -> bf16); enc weights: both dirs contiguous ----
    f2b_kernel<<<256, 256, 0, stream>>>(e0Wih, e0Wb, 1048576 / 4);
    f2b_kernel<<<512, 256, 0, stream>>>(e1Wih, e1Wb, 4194304 / 4);
    f2b_kernel<<<256, 256, 0, stream>>>(d0Wih, d0Wb, 1048576 / 4);
    f2b_kernel<<<512, 256, 0, stream>>>(d1Wih, d1Wb, 4194304 / 4);

    // ---- encoder layer 0 (both dirs in ONE GEMM: N=4096, dir1 cols at 2048) ----
    embed_src_kernel<<<S_LEN * BSZ, 64, 0, stream>>>(sent, emb, x0b);
    gemm_bf16_kernel<<<64 * 32, 256, 0, stream>>>(x0b, e0Wb, e0bih, e0bhh, xwA,
                                                  S_LEN * BSZ, 4096, EMBD, 32, 1, nullptr);
    lstm_mfma_scan<512><<<256, 256, 0, stream>>>(xwA, xwA + 2048 * 64,
                                                 e0Whh, e0Whh + 2048ull * 512,
                                                 nullptr, nullptr, h_e0,
                                                 hsb, cs, S_LEN, 2, 2, bar);
    // ---- encoder layer 1 (final states only) ----
    gemm_bf16_kernel<<<64 * 32, 256, 0, stream>>>(h_e0, e1Wb, e1bih, e1bhh, xwA,
                                                  S_LEN * BSZ, 4096, 2 * HID_, 32, 1, nullptr);
    lstm_mfma_scan<512><<<256, 256, 0, stream>>>(xwA, xwA + 2048 * 64,
                                                 e1Whh, e1Whh + 2048ull * 512,
                                                 nullptr, nullptr, h_e1,
                                                 hsb + 65536, cs + 65536,
                                                 S_LEN, 2, 2, bar + 8192);
    // ---- decoder layer 0 ----
    embed_dec_kernel<<<T_LEN * BSZ, 64, 0, stream>>>(sent, targ, emb, x0b);
    gemm_bf16_kernel<<<32 * 32, 256, 0, stream>>>(x0b, d0Wb, d0bih, d0bhh, xwA,
                                                  T_LEN * BSZ, 4 * DHID_, EMBD, 32, 1, nullptr);
    lstm_mfma_scan<1024><<<256, 256, 0, stream>>>(xwA, nullptr, d0Whh, nullptr,
                                                  hsb, cs, h_d0,
                                                  nullptr, nullptr, T_LEN, 1, 0,
                                                  bar + 2 * 8192);
    // ---- Wout -> bf16 (xwA region free after dec0 scan; stream-ordered) ----
    f2b_kernel<<<2048, 256, 0, stream>>>(Wout, Woutb, (VOC_ * DHID_) / 4);
    // ---- decoder layer 1 ----
    gemm_bf16_kernel<<<32 * 32, 256, 0, stream>>>(h_d0, d1Wb, d1bih, d1bhh, xwB,
                                                  T_LEN * BSZ, 4 * DHID_, DHID_, 32, 1, nullptr);
    lstm_mfma_scan<1024><<<256, 256, 0, stream>>>(xwB, nullptr, d1Whh, nullptr,
                                                  hsb + 65536, cs + 65536, h_d1,
                                                  nullptr, nullptr, T_LEN, 1, 0,
                                                  bar + 3 * 8192);
    // ---- vocab projection (fused softmax partials) + merge + normalize ----
    gemm_bf16_kernel<<<32 * 250, 256, 0, stream>>>(h_d1, Woutb, bout, nullptr, out,
                                                   T_LEN * BSZ, VOC_, DHID_, 250, 0, xwB);
    lsm_merge_kernel<<<T_LEN * BSZ, 256, 0, stream>>>(xwB, ml, 250);
    lsm_norm_kernel<<<T_LEN * BSZ, 256, 0, stream>>>(out, ml, VOC_ / 4);
}

// Round 13
// 2637.238 us; speedup vs baseline: 1.5422x; 1.0160x over previous
//
#include <hip/hip_runtime.h>

#define S_LEN 128
#define T_LEN 64
#define BSZ   64
#define EMBD  256
#define HID_  512
#define DHID_ 1024
#define VOC_  32000
#define HSTR  1024

typedef float  f4_t  __attribute__((ext_vector_type(4)));
typedef float  f32x4 __attribute__((ext_vector_type(4)));
typedef short  s16x8 __attribute__((ext_vector_type(8)));
typedef __bf16 bf16x8 __attribute__((ext_vector_type(8)));
typedef unsigned short u16x4 __attribute__((ext_vector_type(4)));
typedef int    i32x2 __attribute__((ext_vector_type(2)));

// ---------------- workspace layout ----------------
// float offsets:
#define WS_XWA  0ull                       // 16,777,216 fl (enc xw spans XWA+XWB contiguously)
#define WS_XWB  (WS_XWA + 16777216ull)     // 16,777,216 fl
#define WS_CS   (WS_XWB + 16777216ull)     // 131,072 fl (c-state; later ML row constants)
#define WS_BAR  (WS_CS  + 131072ull)       // 32,768 ints (4 regions x 8192)
#define WS_BF   (WS_BAR + 32768ull)
// ushort offsets within bf16 region:
#define U_X0B   0ull
#define U_HE0   (U_X0B + 2097152ull)
#define U_HE1   (U_HE0 + 8388608ull)
#define U_HD0   (U_HE1 + 8388608ull)
#define U_HD1   (U_HD0 + 4194304ull)
#define U_HSB   (U_HD1 + 4194304ull)
#define U_E0W   (U_HSB + 131072ull)
#define U_E1W   (U_E0W + 1048576ull)
#define U_D0W   (U_E1W + 4194304ull)
#define U_D1W   (U_D0W + 1048576ull)

__device__ __forceinline__ unsigned short f2bf(float x) {
    unsigned u = __builtin_bit_cast(unsigned, x);
    return (unsigned short)((u + 0x7fffu + ((u >> 16) & 1u)) >> 16);
}

// ---------------- coherent (LLC-scope) memory helpers ----------------
__device__ __forceinline__ f4_t sc_load4(const void* p) {
    f4_t v;
    asm volatile("global_load_dwordx4 %0, %1, off sc0 sc1" : "=v"(v) : "v"(p));
    return v;                               // NOT ready until a vmcnt wait
}
__device__ __forceinline__ int sc_load1(const int* p) {
    int v;
    asm volatile("global_load_dword %0, %1, off sc0 sc1\n\ts_waitcnt vmcnt(0)"
                 : "=v"(v) : "v"(p) : "memory");
    return v;
}
__device__ __forceinline__ void sc_store_int(int* p, int v) {
    asm volatile("global_store_dword %0, %1, off sc0 sc1" :: "v"(p), "v"(v) : "memory");
}
__device__ __forceinline__ void sc_store8(void* p, i32x2 v) {
    asm volatile("global_store_dwordx2 %0, %1, off sc0 sc1" :: "v"(p), "v"(v) : "memory");
}
__device__ __forceinline__ float g_load1(const float* p) {   // plain cached load, no wait
    float v;
    asm volatile("global_load_dword %0, %1, off" : "=v"(v) : "v"(p));
    return v;
}
__device__ __forceinline__ void wait_vm0() {
    asm volatile("s_waitcnt vmcnt(0)" ::: "memory");
}
__device__ __forceinline__ void wait_vm8() {
    asm volatile("s_waitcnt vmcnt(8)" ::: "memory");
}

__device__ __forceinline__ void gload_lds16(const void* g, void* l) {
    __builtin_amdgcn_global_load_lds(
        (const __attribute__((address_space(1))) void*)g,
        (__attribute__((address_space(3))) void*)l, 16, 0, 0);
}

__device__ __forceinline__ float sigmoidf_(float x) { return 1.f / (1.f + expf(-x)); }

// ---------------- fp32 -> bf16 conversion (single kernel, 4 weight segments) ----------------
__global__ __launch_bounds__(256) void f2b_multi_kernel(
    const float* __restrict__ p0, unsigned short* __restrict__ q0,   // 262144 n4
    const float* __restrict__ p1, unsigned short* __restrict__ q1,   // 1048576 n4
    const float* __restrict__ p2, unsigned short* __restrict__ q2,   // 262144 n4
    const float* __restrict__ p3, unsigned short* __restrict__ q3)   // 1048576 n4
{
    const int stride = gridDim.x * 256;
    for (int i = blockIdx.x * 256 + threadIdx.x; i < 2621440; i += stride) {
        const float* in; unsigned short* out; int o;
        if (i < 262144)       { in = p0; out = q0; o = i; }
        else if (i < 1310720) { in = p1; out = q1; o = i - 262144; }
        else if (i < 1572864) { in = p2; out = q2; o = i - 1310720; }
        else                  { in = p3; out = q3; o = i - 1572864; }
        const float4 v = reinterpret_cast<const float4*>(in)[o];
        u16x4 w = { f2bf(v.x), f2bf(v.y), f2bf(v.z), f2bf(v.w) };
        reinterpret_cast<u16x4*>(out)[o] = w;
    }
}

__global__ __launch_bounds__(256) void f2b_kernel(
    const float* __restrict__ in, unsigned short* __restrict__ out, int n4)
{
    const int stride = gridDim.x * 256;
    for (int i = blockIdx.x * 256 + threadIdx.x; i < n4; i += stride) {
        const float4 v = reinterpret_cast<const float4*>(in)[i];
        u16x4 o = { f2bf(v.x), f2bf(v.y), f2bf(v.z), f2bf(v.w) };
        reinterpret_cast<u16x4*>(out)[i] = o;
    }
}

// ---------------- embedding gathers (emit bf16), 4 tokens per 256-thr block ----------------
__global__ __launch_bounds__(256) void embed_src_kernel(
    const int* __restrict__ toks, const float* __restrict__ emb,
    unsigned short* __restrict__ out)
{
    const int i = blockIdx.x * 4 + (threadIdx.x >> 6);
    const int lane = threadIdx.x & 63;
    const int tok = toks[i];
    const float4 v = reinterpret_cast<const float4*>(emb + (size_t)tok * EMBD)[lane];
    u16x4 o = { f2bf(v.x), f2bf(v.y), f2bf(v.z), f2bf(v.w) };
    reinterpret_cast<u16x4*>(out + (size_t)i * EMBD)[lane] = o;
}

__global__ __launch_bounds__(256) void embed_dec_kernel(
    const int* __restrict__ sent, const int* __restrict__ targ,
    const float* __restrict__ emb, unsigned short* __restrict__ out)
{
    const int i = blockIdx.x * 4 + (threadIdx.x >> 6);
    const int lane = threadIdx.x & 63;
    const int t = i >> 6, b = i & 63;
    const int tok = (t == 0) ? sent[(S_LEN - 1) * BSZ + b] : targ[(t - 1) * BSZ + b];
    const float4 v = reinterpret_cast<const float4*>(emb + (size_t)tok * EMBD)[lane];
    u16x4 o = { f2bf(v.x), f2bf(v.y), f2bf(v.z), f2bf(v.w) };
    reinterpret_cast<u16x4*>(out + (size_t)i * EMBD)[lane] = o;
}

// ---------------- bf16 MFMA GEMM:  C = A[M,K] * B[N,K]^T + b1 (+ b2) ----------------
// tmode 0: C fp32 row-major (M,N). tmode 1: C fp32 as (M/64, N, 64) = (T,N,B).
// part (tmode 0 only, nullable): per-(row, col-tile) log-softmax partials
// (max, sumexp) written as part[(row*nTN + bn/128)*2 + {0,1}].
__global__ __launch_bounds__(256) void gemm_bf16_kernel(
    const unsigned short* __restrict__ A, const unsigned short* __restrict__ B,
    const float* __restrict__ b1, const float* __restrict__ b2,
    float* __restrict__ C, int M, int N, int K, int nTN, int tmode,
    float* __restrict__ part)
{
    __shared__ __align__(16) unsigned short As[128 * 64];
    __shared__ __align__(16) unsigned short Bs[128 * 64];
    __shared__ float prt[2][128][2];

    const int tid  = threadIdx.x;
    const int lane = tid & 63;
    const int wv   = tid >> 6;
    const int wm   = wv >> 1, wn = wv & 1;

    const int nwg = gridDim.x;
    const int q = nwg >> 3, r = nwg & 7;
    const int xcd = blockIdx.x & 7, io = blockIdx.x >> 3;
    const int wg = (xcd < r ? xcd * (q + 1) : r * (q + 1) + (xcd - r) * q) + io;
    const int bm = (wg / nTN) * 128;
    const int bn = (wg % nTN) * 128;

    f32x4 acc[4][4];
#pragma unroll
    for (int i = 0; i < 4; ++i)
#pragma unroll
        for (int j = 0; j < 4; ++j) acc[i][j] = (f32x4)0.f;

    const int lin_base = wv * 1024 + lane * 16;

    for (int k0 = 0; k0 < K; k0 += 64) {
        __syncthreads();
#pragma unroll
        for (int qc = 0; qc < 4; ++qc) {
            const int lin = qc * 4096 + lin_base;
            const int row = lin >> 7;
            const int c   = (lin >> 4) & 7;
            const int sc  = c ^ (row & 7);
            const size_t gofs  = (size_t)(bm + row) * K + k0 + sc * 8;
            const size_t gofsB = (size_t)(bn + row) * K + k0 + sc * 8;
            char* ldst  = (char*)As + qc * 4096 + wv * 1024;
            char* ldstB = (char*)Bs + qc * 4096 + wv * 1024;
            gload_lds16(A + gofs, ldst);
            gload_lds16(B + gofsB, ldstB);
        }
        asm volatile("s_waitcnt vmcnt(0)" ::: "memory");
        __syncthreads();
#pragma unroll
        for (int ks = 0; ks < 2; ++ks) {
            bf16x8 af[4], bfv[4];
            const int ca = ks * 4 + (lane >> 4);
#pragma unroll
            for (int f = 0; f < 4; ++f) {
                const int ra = wm * 64 + f * 16 + (lane & 15);
                af[f] = __builtin_bit_cast(bf16x8,
                    *(const s16x8*)((const char*)As + ra * 128 + ((ca ^ (ra & 7)) << 4)));
                const int rb = wn * 64 + f * 16 + (lane & 15);
                bfv[f] = __builtin_bit_cast(bf16x8,
                    *(const s16x8*)((const char*)Bs + rb * 128 + ((ca ^ (rb & 7)) << 4)));
            }
#pragma unroll
            for (int i = 0; i < 4; ++i)
#pragma unroll
                for (int j = 0; j < 4; ++j)
                    acc[i][j] = __builtin_amdgcn_mfma_f32_16x16x32_bf16(
                        af[i], bfv[j], acc[i][j], 0, 0, 0);
        }
    }

    const int col0 = bn + wn * 64 + (lane & 15);
    if (tmode == 0) {
        const int row0 = bm + wm * 64 + ((lane >> 4) << 2);
        float bs[4];
#pragma unroll
        for (int j = 0; j < 4; ++j) {
            const int col = col0 + j * 16;
            bs[j] = b1[col];
            if (b2) bs[j] += b2[col];
        }
#pragma unroll
        for (int i = 0; i < 4; ++i)
#pragma unroll
            for (int j = 0; j < 4; ++j)
#pragma unroll
                for (int rg = 0; rg < 4; ++rg)
                    C[(size_t)(row0 + i * 16 + rg) * N + col0 + j * 16] = acc[i][j][rg] + bs[j];

        if (part) {
            float pm[4][4], ps[4][4];
#pragma unroll
            for (int i = 0; i < 4; ++i)
#pragma unroll
                for (int rg = 0; rg < 4; ++rg) {
                    float m = acc[i][0][rg] + bs[0];
                    m = fmaxf(m, acc[i][1][rg] + bs[1]);
                    m = fmaxf(m, acc[i][2][rg] + bs[2]);
                    m = fmaxf(m, acc[i][3][rg] + bs[3]);
                    pm[i][rg] = m;
                }
#pragma unroll
            for (int mask = 1; mask <= 8; mask <<= 1)
#pragma unroll
                for (int i = 0; i < 4; ++i)
#pragma unroll
                    for (int rg = 0; rg < 4; ++rg)
                        pm[i][rg] = fmaxf(pm[i][rg], __shfl_xor(pm[i][rg], mask));
#pragma unroll
            for (int i = 0; i < 4; ++i)
#pragma unroll
                for (int rg = 0; rg < 4; ++rg) {
                    float s = 0.f;
#pragma unroll
                    for (int j = 0; j < 4; ++j)
                        s += expf(acc[i][j][rg] + bs[j] - pm[i][rg]);
                    ps[i][rg] = s;
                }
#pragma unroll
            for (int mask = 1; mask <= 8; mask <<= 1)
#pragma unroll
                for (int i = 0; i < 4; ++i)
#pragma unroll
                    for (int rg = 0; rg < 4; ++rg)
                        ps[i][rg] += __shfl_xor(ps[i][rg], mask);
            if ((lane & 15) == 0) {
#pragma unroll
                for (int i = 0; i < 4; ++i)
#pragma unroll
                    for (int rg = 0; rg < 4; ++rg) {
                        const int r64 = ((lane >> 4) << 2) + i * 16 + rg;
                        prt[wn][wm * 64 + r64][0] = pm[i][rg];
                        prt[wn][wm * 64 + r64][1] = ps[i][rg];
                    }
            }
            __syncthreads();
            if (tid < 128) {
                const float m0_ = prt[0][tid][0], s0_ = prt[0][tid][1];
                const float m1_ = prt[1][tid][0], s1_ = prt[1][tid][1];
                const float Mx = fmaxf(m0_, m1_);
                const float Sx = s0_ * expf(m0_ - Mx) + s1_ * expf(m1_ - Mx);
                const size_t o = ((size_t)(bm + tid) * nTN + (bn >> 7)) * 2;
                part[o] = Mx; part[o + 1] = Sx;
            }
        }
    } else {
        const int tblk = (bm >> 6) + wm;
        const int rb = (lane >> 4) << 2;
#pragma unroll
        for (int i = 0; i < 4; ++i) {
#pragma unroll
            for (int j = 0; j < 4; ++j) {
                const int col = col0 + j * 16;
                float bias = b1[col];
                if (b2) bias += b2[col];
                float4 v = { acc[i][j][0] + bias, acc[i][j][1] + bias,
                             acc[i][j][2] + bias, acc[i][j][3] + bias };
                *reinterpret_cast<float4*>(&C[((size_t)tblk * N + col) * 64 + rb + i * 16]) = v;
            }
        }
    }
}

// ---------------- persistent MFMA LSTM scan, single-hop flag sync ----------------
// Grid 256x256. hist: (T,B,1024) bf16. xw: fp32 (T, 4096, B) — t-stride 4096 always.
// Per-step barriers trimmed to 4: poll, post-staging, pre-exchange, pre-hpack-store.
// Flag ordering: all h stores + flag are wave 0's own ops; vmcnt(0) in wave 0 orders them.
template<int H_T>
__global__ __launch_bounds__(256, 1) void lstm_mfma_scan(
    const float* __restrict__ xw0, const float* __restrict__ xw1,
    const float* __restrict__ Whh0, const float* __restrict__ Whh1,
    const unsigned short* __restrict__ h0b, const float* __restrict__ c0,
    unsigned short* __restrict__ hist,
    unsigned short* __restrict__ hsb, float* __restrict__ csd,
    int T, int ndir, int rev_mask, int* bar)
{
    constexpr int KST = H_T / 32;
    constexpr int CH  = H_T / 8;
    constexpr int NB  = (64 * CH) / 2048;

    __shared__ __align__(16) unsigned short h_lds[64 * H_T];
    __shared__ float pre[64][17];
    __shared__ __align__(8) unsigned short hpack[64][4];

    const int tid  = threadIdx.x;
    const int lane = tid & 63;
    const int w    = tid >> 6;
    const int bpd  = (ndir == 2) ? 128 : 256;
    const int dir  = blockIdx.x / bpd;
    const int blk  = blockIdx.x - dir * bpd;
    const int m0   = blk * 4;
    const int rev  = (rev_mask >> dir) & 1;
    const float* xw  = dir ? xw1  : xw0;
    const float* Whh = dir ? Whh1 : Whh0;
    const int dcol = dir * H_T;
    const int b = tid & 63;
    const int j = tid >> 6;

    int* myflag = bar + blockIdx.x * 32;
    const int* pollflag = bar + (dir * bpd + (tid < bpd ? tid : 0)) * 32;
    const bool polls = (tid < bpd);

    // ---- B-fragments: Whh rows in registers, bf16 ----
    const int n  = lane & 15;           // (gate,cell) = (n>>2, n&3)
    const int kg = lane >> 4;
    const int wr = (n >> 2) * H_T + m0 + (n & 3);
    s16x8 wfr[KST];
#pragma unroll
    for (int ks = 0; ks < KST; ++ks) {
        const float* wp = Whh + (size_t)wr * H_T + ks * 32 + kg * 8;
        const float4 lo = *reinterpret_cast<const float4*>(wp);
        const float4 hi = *reinterpret_cast<const float4*>(wp + 4);
        s16x8 rr;
        rr[0] = (short)f2bf(lo.x); rr[1] = (short)f2bf(lo.y);
        rr[2] = (short)f2bf(lo.z); rr[3] = (short)f2bf(lo.w);
        rr[4] = (short)f2bf(hi.x); rr[5] = (short)f2bf(hi.y);
        rr[6] = (short)f2bf(hi.z); rr[7] = (short)f2bf(hi.w);
        wfr[ks] = rr;
    }

    float c  = c0 ? c0[(size_t)b * HSTR + dcol + m0 + j] : 0.f;
    float hn = 0.f;
    const int rA  = w * 16 + n;
    const int rAx = rA & 7;

    for (int s = 0; s < T; ++s) {
        const int tt = rev ? (T - 1 - s) : s;

        // coalesced xw gate loads: layout (tt, 4096, b)
        const float* xb = xw + ((size_t)tt * 4096 + m0 + j) * 64 + b;
        float xg0 = g_load1(xb);
        float xg1 = g_load1(xb + (size_t)H_T * 64);
        float xg2 = g_load1(xb + (size_t)2 * H_T * 64);
        float xg3 = g_load1(xb + (size_t)3 * H_T * 64);

        // single-hop: wait for all producers of step s-1
        if (s > 0) {
            int ok = polls ? 0 : 1;
            for (;;) {
                if (!ok) ok = (sc_load1(pollflag) >= s) ? 1 : 0;
                if (__syncthreads_and(ok)) break;
            }
        }

        const unsigned short* hb;
        size_t tofs;
        if (s == 0) { hb = h0b; tofs = 0; }
        else {
            const int tp = rev ? (tt + 1) : (tt - 1);
            hb = hist; tofs = (size_t)tp * (64 * 1024);
        }

        float p0 = 0.f, p1 = 0.f, p2 = 0.f, p3 = 0.f;
        if (hb) {
            // ---- stage h tile: sc_load4 -> XOR-swizzled LDS, 2-deep counted pipeline ----
            f4_t bufA[8], bufB[8];
            auto issue = [&](f4_t (&bf)[8], int bt) {
#pragma unroll
                for (int jj = 0; jj < 8; ++jj) {
                    const int idx = (bt * 8 + jj) * 256 + tid;
                    const int rr_ = idx / CH, cc_ = idx % CH;
                    bf[jj] = sc_load4(hb + tofs + (size_t)rr_ * 1024 + dcol + cc_ * 8);
                }
            };
            auto writeb = [&](const f4_t (&bf)[8], int bt) {
#pragma unroll
                for (int jj = 0; jj < 8; ++jj) {
                    const int idx = (bt * 8 + jj) * 256 + tid;
                    const int rr_ = idx / CH, cc_ = idx % CH;
                    const int off = rr_ * (2 * H_T) + ((cc_ ^ (rr_ & 7)) << 4);
                    *(f4_t*)((char*)h_lds + off) = bf[jj];
                }
            };
            issue(bufA, 0);
            if (NB > 1) issue(bufB, 1);
#pragma unroll
            for (int bt = 0; bt < NB; ++bt) {
                if (bt + 1 < NB) wait_vm8(); else wait_vm0();
                if (bt & 1) writeb(bufB, bt); else writeb(bufA, bt);
                if (bt + 2 < NB) { if (bt & 1) issue(bufB, bt + 2); else issue(bufA, bt + 2); }
            }
            __syncthreads();

            // ---- MFMA: D[batch][n] += h[batch][k] * W[wr(n)][k] ----
            f32x4 acc = {0.f, 0.f, 0.f, 0.f};
#pragma unroll
            for (int ks = 0; ks < KST; ++ks) {
                const int cc_ = ks * 4 + kg;
                const int off = rA * (2 * H_T) + ((cc_ ^ rAx) << 4);
                const bf16x8 a = __builtin_bit_cast(bf16x8,
                    *(const s16x8*)((const char*)h_lds + off));
                acc = __builtin_amdgcn_mfma_f32_16x16x32_bf16(
                    a, __builtin_bit_cast(bf16x8, wfr[ks]), acc, 0, 0, 0);
            }
            // ---- exchange D -> (b, gate) layout (prev-step reads separated by poll barrier) ----
#pragma unroll
            for (int rg = 0; rg < 4; ++rg)
                pre[w * 16 + kg * 4 + rg][n] = acc[rg];
            __syncthreads();
            p0 = pre[b][0 + j]; p1 = pre[b][4 + j];
            p2 = pre[b][8 + j]; p3 = pre[b][12 + j];
        }

        asm volatile("s_waitcnt vmcnt(0)"
                     : "+v"(xg0), "+v"(xg1), "+v"(xg2), "+v"(xg3) :: "memory");

        const float ig = sigmoidf_(p0 + xg0);
        const float fg = sigmoidf_(p1 + xg1);
        const float gg = tanhf(p2 + xg2);
        const float og = sigmoidf_(p3 + xg3);
        c  = fg * c + ig * gg;
        hn = og * tanhf(c);

        // pack 4 cells x 64 batches in LDS -> 64 coherent 8B stores (all wave 0)
        hpack[b][j] = f2bf(hn);
        __syncthreads();
        if (tid < 64) {
            const i32x2 v2 = *reinterpret_cast<const i32x2*>(&hpack[tid][0]);
            sc_store8(hist + (size_t)tt * (64 * 1024) + (size_t)tid * 1024 + dcol + m0, v2);
        }
        wait_vm0();               // wave 0: its own 64 h-stores drained before its flag
        if (s + 1 < T && tid == 0) sc_store_int(myflag, s + 1);
    }

    if (hsb) hsb[(size_t)b * 1024 + dcol + m0 + j] = f2bf(hn);
    if (csd) csd[(size_t)b * HSTR + dcol + m0 + j] = c;
}

// ---------------- log-softmax: merge partials (2KB, L2-hot) + normalize, one kernel ----------------
__global__ __launch_bounds__(256) void lsm_norm_kernel(
    float* __restrict__ x, const float* __restrict__ part, int nt, int n4)
{
    __shared__ float ms[256], ss[256];
    const int tid = threadIdx.x;
    float m = -3.0e38f, s = 0.f;
    for (int t = tid; t < nt; t += 256) {
        const float mo = part[((size_t)blockIdx.x * nt + t) * 2];
        const float so = part[((size_t)blockIdx.x * nt + t) * 2 + 1];
        const float M = fmaxf(m, mo);
        s = s * expf(m - M) + so * expf(mo - M);
        m = M;
    }
    ms[tid] = m; ss[tid] = s;
    __syncthreads();
    for (int off = 128; off > 0; off >>= 1) {
        if (tid < off) {
            const float m2 = ms[tid + off], s2 = ss[tid + off];
            const float m1 = ms[tid],       s1 = ss[tid];
            const float M = fmaxf(m1, m2);
            ss[tid] = s1 * expf(m1 - M) + s2 * expf(m2 - M);
            ms[tid] = M;
        }
        __syncthreads();
    }
    const float ML = ms[0] + logf(ss[0]);
    float4* p = reinterpret_cast<float4*>(x + (size_t)blockIdx.x * (n4 * 4));
    for (int cc = tid; cc < n4; cc += 256) {
        float4 v = p[cc];
        v.x -= ML; v.y -= ML; v.z -= ML; v.w -= ML;
        p[cc] = v;
    }
}

// ---------------- host-side orchestration ----------------
extern "C" void kernel_launch(void* const* d_in, const int* in_sizes, int n_in,
                              void* d_out, int out_size, void* d_ws, size_t ws_size,
                              hipStream_t stream)
{
    const int*   sent  = (const int*)d_in[0];
    const int*   targ  = (const int*)d_in[1];
    const float* emb   = (const float*)d_in[2];
    const float* e0Wih = (const float*)d_in[3];
    const float* e0Whh = (const float*)d_in[4];
    const float* e0bih = (const float*)d_in[5];
    const float* e0bhh = (const float*)d_in[6];
    const float* e1Wih = (const float*)d_in[7];
    const float* e1Whh = (const float*)d_in[8];
    const float* e1bih = (const float*)d_in[9];
    const float* e1bhh = (const float*)d_in[10];
    const float* d0Wih = (const float*)d_in[11];
    const float* d0Whh = (const float*)d_in[12];
    const float* d0bih = (const float*)d_in[13];
    const float* d0bhh = (const float*)d_in[14];
    const float* d1Wih = (const float*)d_in[15];
    const float* d1Whh = (const float*)d_in[16];
    const float* d1bih = (const float*)d_in[17];
    const float* d1bhh = (const float*)d_in[18];
    const float* Wout  = (const float*)d_in[19];
    const float* bout  = (const float*)d_in[20];

    float* ws  = (float*)d_ws;
    float* xwA = ws + WS_XWA;               // enc xw spans XWA+XWB (33.5M fl)
    float* xwB = ws + WS_XWB;               // dec1 xw; later softmax partials
    float* cs  = ws + WS_CS;
    int*   bar = (int*)(ws + WS_BAR);
    unsigned short* ub    = (unsigned short*)(ws + WS_BF);
    unsigned short* x0b   = ub + U_X0B;
    unsigned short* h_e0  = ub + U_HE0;
    unsigned short* h_e1  = ub + U_HE1;
    unsigned short* h_d0  = ub + U_HD0;
    unsigned short* h_d1  = ub + U_HD1;
    unsigned short* hsb   = ub + U_HSB;
    unsigned short* e0Wb  = ub + U_E0W;
    unsigned short* e1Wb  = ub + U_E1W;
    unsigned short* d0Wb  = ub + U_D0W;
    unsigned short* d1Wb  = ub + U_D1W;
    unsigned short* Woutb = (unsigned short*)xwA;   // reused after dec0 scan
    float* out = (float*)d_out;

    hipMemsetAsync(bar, 0, 4 * 8192 * sizeof(int), stream);

    // ---- weight conversions (fp32 -> bf16), one kernel ----
    f2b_multi_kernel<<<1280, 256, 0, stream>>>(e0Wih, e0Wb, e1Wih, e1Wb,
                                               d0Wih, d0Wb, d1Wih, d1Wb);

    // ---- encoder layer 0 (both dirs in ONE GEMM: N=4096, dir1 cols at 2048) ----
    embed_src_kernel<<<(S_LEN * BSZ) / 4, 256, 0, stream>>>(sent, emb, x0b);
    gemm_bf16_kernel<<<64 * 32, 256, 0, stream>>>(x0b, e0Wb, e0bih, e0bhh, xwA,
                                                  S_LEN * BSZ, 4096, EMBD, 32, 1, nullptr);
    lstm_mfma_scan<512><<<256, 256, 0, stream>>>(xwA, xwA + 2048 * 64,
                                                 e0Whh, e0Whh + 2048ull * 512,
                                                 nullptr, nullptr, h_e0,
                                                 hsb, cs, S_LEN, 2, 2, bar);
    // ---- encoder layer 1 (final states only) ----
    gemm_bf16_kernel<<<64 * 32, 256, 0, stream>>>(h_e0, e1Wb, e1bih, e1bhh, xwA,
                                                  S_LEN * BSZ, 4096, 2 * HID_, 32, 1, nullptr);
    lstm_mfma_scan<512><<<256, 256, 0, stream>>>(xwA, xwA + 2048 * 64,
                                                 e1Whh, e1Whh + 2048ull * 512,
                                                 nullptr, nullptr, h_e1,
                                                 hsb + 65536, cs + 65536,
                                                 S_LEN, 2, 2, bar + 8192);
    // ---- decoder layer 0 ----
    embed_dec_kernel<<<(T_LEN * BSZ) / 4, 256, 0, stream>>>(sent, targ, emb, x0b);
    gemm_bf16_kernel<<<32 * 32, 256, 0, stream>>>(x0b, d0Wb, d0bih, d0bhh, xwA,
                                                  T_LEN * BSZ, 4 * DHID_, EMBD, 32, 1, nullptr);
    lstm_mfma_scan<1024><<<256, 256, 0, stream>>>(xwA, nullptr, d0Whh, nullptr,
                                                  hsb, cs, h_d0,
                                                  nullptr, nullptr, T_LEN, 1, 0,
                                                  bar + 2 * 8192);
    // ---- Wout -> bf16 (xwA region free after dec0 scan; stream-ordered) ----
    f2b_kernel<<<2048, 256, 0, stream>>>(Wout, Woutb, (VOC_ * DHID_) / 4);
    // ---- decoder layer 1 ----
    gemm_bf16_kernel<<<32 * 32, 256, 0, stream>>>(h_d0, d1Wb, d1bih, d1bhh, xwB,
                                                  T_LEN * BSZ, 4 * DHID_, DHID_, 32, 1, nullptr);
    lstm_mfma_scan<1024><<<256, 256, 0, stream>>>(xwB, nullptr, d1Whh, nullptr,
                                                  hsb + 65536, cs + 65536, h_d1,
                                                  nullptr, nullptr, T_LEN, 1, 0,
                                                  bar + 3 * 8192);
    // ---- vocab projection (fused softmax partials) + merge+normalize ----
    gemm_bf16_kernel<<<32 * 250, 256, 0, stream>>>(h_d1, Woutb, bout, nullptr, out,
                                                   T_LEN * BSZ, VOC_, DHID_, 250, 0, xwB);
    lsm_norm_kernel<<<T_LEN * BSZ, 256, 0, stream>>>(out, xwB, 250, VOC_ / 4);
}

// Round 14
// 2527.236 us; speedup vs baseline: 1.6093x; 1.0435x over previous
//
#include <hip/hip_runtime.h>

#define S_LEN 128
#define T_LEN 64
#define BSZ   64
#define EMBD  256
#define HID_  512
#define DHID_ 1024
#define VOC_  32000
#define HSTR  1024

typedef float  f4_t  __attribute__((ext_vector_type(4)));
typedef float  f32x4 __attribute__((ext_vector_type(4)));
typedef short  s16x8 __attribute__((ext_vector_type(8)));
typedef __bf16 bf16x8 __attribute__((ext_vector_type(8)));
typedef unsigned short u16x4 __attribute__((ext_vector_type(4)));
typedef int    i32x2 __attribute__((ext_vector_type(2)));

// ---------------- workspace layout ----------------
// float offsets:
#define WS_XWA  0ull                       // 16,777,216 fl (enc xw spans XWA+XWB contiguously)
#define WS_XWB  (WS_XWA + 16777216ull)     // 16,777,216 fl
#define WS_CS   (WS_XWB + 16777216ull)     // 131,072 fl
#define WS_BAR  (WS_CS  + 131072ull)       // 32,768 ints (4 regions x 8192)
#define WS_BF   (WS_BAR + 32768ull)
// ushort offsets within bf16 region:
#define U_X0B   0ull
#define U_HE0   (U_X0B + 2097152ull)
#define U_HE1   (U_HE0 + 8388608ull)
#define U_HD0   (U_HE1 + 8388608ull)
#define U_HD1   (U_HD0 + 4194304ull)
#define U_HSB   (U_HD1 + 4194304ull)
#define U_E0W   (U_HSB + 131072ull)
#define U_E1W   (U_E0W + 1048576ull)
#define U_D0W   (U_E1W + 4194304ull)
#define U_D1W   (U_D0W + 1048576ull)

__device__ __forceinline__ unsigned short f2bf(float x) {
    unsigned u = __builtin_bit_cast(unsigned, x);
    return (unsigned short)((u + 0x7fffu + ((u >> 16) & 1u)) >> 16);
}

// ---------------- coherent (LLC-scope) memory helpers ----------------
__device__ __forceinline__ f4_t sc_load4(const void* p) {
    f4_t v;
    asm volatile("global_load_dwordx4 %0, %1, off sc0 sc1" : "=v"(v) : "v"(p));
    return v;                               // NOT ready until a vmcnt wait
}
__device__ __forceinline__ int sc_load1(const int* p) {
    int v;
    asm volatile("global_load_dword %0, %1, off sc0 sc1\n\ts_waitcnt vmcnt(0)"
                 : "=v"(v) : "v"(p) : "memory");
    return v;
}
__device__ __forceinline__ void sc_store_int(int* p, int v) {
    asm volatile("global_store_dword %0, %1, off sc0 sc1" :: "v"(p), "v"(v) : "memory");
}
__device__ __forceinline__ void sc_store8(void* p, i32x2 v) {
    asm volatile("global_store_dwordx2 %0, %1, off sc0 sc1" :: "v"(p), "v"(v) : "memory");
}
__device__ __forceinline__ float g_load1(const float* p) {   // plain cached load, no wait
    float v;
    asm volatile("global_load_dword %0, %1, off" : "=v"(v) : "v"(p));
    return v;
}
__device__ __forceinline__ void wait_vm0() {
    asm volatile("s_waitcnt vmcnt(0)" ::: "memory");
}
__device__ __forceinline__ void wait_vm8() {
    asm volatile("s_waitcnt vmcnt(8)" ::: "memory");
}

__device__ __forceinline__ void gload_lds16(const void* g, void* l) {
    __builtin_amdgcn_global_load_lds(
        (const __attribute__((address_space(1))) void*)g,
        (__attribute__((address_space(3))) void*)l, 16, 0, 0);
}

__device__ __forceinline__ float sigmoidf_(float x) { return 1.f / (1.f + expf(-x)); }

// ---------------- fp32 -> bf16 conversion (single kernel, 4 weight segments) ----------------
__global__ __launch_bounds__(256) void f2b_multi_kernel(
    const float* __restrict__ p0, unsigned short* __restrict__ q0,
    const float* __restrict__ p1, unsigned short* __restrict__ q1,
    const float* __restrict__ p2, unsigned short* __restrict__ q2,
    const float* __restrict__ p3, unsigned short* __restrict__ q3)
{
    const int stride = gridDim.x * 256;
    for (int i = blockIdx.x * 256 + threadIdx.x; i < 2621440; i += stride) {
        const float* in; unsigned short* out; int o;
        if (i < 262144)       { in = p0; out = q0; o = i; }
        else if (i < 1310720) { in = p1; out = q1; o = i - 262144; }
        else if (i < 1572864) { in = p2; out = q2; o = i - 1310720; }
        else                  { in = p3; out = q3; o = i - 1572864; }
        const float4 v = reinterpret_cast<const float4*>(in)[o];
        u16x4 w = { f2bf(v.x), f2bf(v.y), f2bf(v.z), f2bf(v.w) };
        reinterpret_cast<u16x4*>(out)[o] = w;
    }
}

__global__ __launch_bounds__(256) void f2b_kernel(
    const float* __restrict__ in, unsigned short* __restrict__ out, int n4)
{
    const int stride = gridDim.x * 256;
    for (int i = blockIdx.x * 256 + threadIdx.x; i < n4; i += stride) {
        const float4 v = reinterpret_cast<const float4*>(in)[i];
        u16x4 o = { f2bf(v.x), f2bf(v.y), f2bf(v.z), f2bf(v.w) };
        reinterpret_cast<u16x4*>(out)[i] = o;
    }
}

// ---------------- embedding gathers (emit bf16), 4 tokens per 256-thr block ----------------
__global__ __launch_bounds__(256) void embed_src_kernel(
    const int* __restrict__ toks, const float* __restrict__ emb,
    unsigned short* __restrict__ out)
{
    const int i = blockIdx.x * 4 + (threadIdx.x >> 6);
    const int lane = threadIdx.x & 63;
    const int tok = toks[i];
    const float4 v = reinterpret_cast<const float4*>(emb + (size_t)tok * EMBD)[lane];
    u16x4 o = { f2bf(v.x), f2bf(v.y), f2bf(v.z), f2bf(v.w) };
    reinterpret_cast<u16x4*>(out + (size_t)i * EMBD)[lane] = o;
}

__global__ __launch_bounds__(256) void embed_dec_kernel(
    const int* __restrict__ sent, const int* __restrict__ targ,
    const float* __restrict__ emb, unsigned short* __restrict__ out)
{
    const int i = blockIdx.x * 4 + (threadIdx.x >> 6);
    const int lane = threadIdx.x & 63;
    const int t = i >> 6, b = i & 63;
    const int tok = (t == 0) ? sent[(S_LEN - 1) * BSZ + b] : targ[(t - 1) * BSZ + b];
    const float4 v = reinterpret_cast<const float4*>(emb + (size_t)tok * EMBD)[lane];
    u16x4 o = { f2bf(v.x), f2bf(v.y), f2bf(v.z), f2bf(v.w) };
    reinterpret_cast<u16x4*>(out + (size_t)i * EMBD)[lane] = o;
}

// ---------------- bf16 MFMA GEMM:  C = A[M,K] * B[N,K]^T + b1 (+ b2) ----------------
__global__ __launch_bounds__(256) void gemm_bf16_kernel(
    const unsigned short* __restrict__ A, const unsigned short* __restrict__ B,
    const float* __restrict__ b1, const float* __restrict__ b2,
    float* __restrict__ C, int M, int N, int K, int nTN, int tmode,
    float* __restrict__ part)
{
    __shared__ __align__(16) unsigned short As[128 * 64];
    __shared__ __align__(16) unsigned short Bs[128 * 64];
    __shared__ float prt[2][128][2];

    const int tid  = threadIdx.x;
    const int lane = tid & 63;
    const int wv   = tid >> 6;
    const int wm   = wv >> 1, wn = wv & 1;

    const int nwg = gridDim.x;
    const int q = nwg >> 3, r = nwg & 7;
    const int xcd = blockIdx.x & 7, io = blockIdx.x >> 3;
    const int wg = (xcd < r ? xcd * (q + 1) : r * (q + 1) + (xcd - r) * q) + io;
    const int bm = (wg / nTN) * 128;
    const int bn = (wg % nTN) * 128;

    f32x4 acc[4][4];
#pragma unroll
    for (int i = 0; i < 4; ++i)
#pragma unroll
        for (int j = 0; j < 4; ++j) acc[i][j] = (f32x4)0.f;

    const int lin_base = wv * 1024 + lane * 16;

    for (int k0 = 0; k0 < K; k0 += 64) {
        __syncthreads();
#pragma unroll
        for (int qc = 0; qc < 4; ++qc) {
            const int lin = qc * 4096 + lin_base;
            const int row = lin >> 7;
            const int c   = (lin >> 4) & 7;
            const int sc  = c ^ (row & 7);
            const size_t gofs  = (size_t)(bm + row) * K + k0 + sc * 8;
            const size_t gofsB = (size_t)(bn + row) * K + k0 + sc * 8;
            char* ldst  = (char*)As + qc * 4096 + wv * 1024;
            char* ldstB = (char*)Bs + qc * 4096 + wv * 1024;
            gload_lds16(A + gofs, ldst);
            gload_lds16(B + gofsB, ldstB);
        }
        asm volatile("s_waitcnt vmcnt(0)" ::: "memory");
        __syncthreads();
#pragma unroll
        for (int ks = 0; ks < 2; ++ks) {
            bf16x8 af[4], bfv[4];
            const int ca = ks * 4 + (lane >> 4);
#pragma unroll
            for (int f = 0; f < 4; ++f) {
                const int ra = wm * 64 + f * 16 + (lane & 15);
                af[f] = __builtin_bit_cast(bf16x8,
                    *(const s16x8*)((const char*)As + ra * 128 + ((ca ^ (ra & 7)) << 4)));
                const int rb = wn * 64 + f * 16 + (lane & 15);
                bfv[f] = __builtin_bit_cast(bf16x8,
                    *(const s16x8*)((const char*)Bs + rb * 128 + ((ca ^ (rb & 7)) << 4)));
            }
#pragma unroll
            for (int i = 0; i < 4; ++i)
#pragma unroll
                for (int j = 0; j < 4; ++j)
                    acc[i][j] = __builtin_amdgcn_mfma_f32_16x16x32_bf16(
                        af[i], bfv[j], acc[i][j], 0, 0, 0);
        }
    }

    const int col0 = bn + wn * 64 + (lane & 15);
    if (tmode == 0) {
        const int row0 = bm + wm * 64 + ((lane >> 4) << 2);
        float bs[4];
#pragma unroll
        for (int j = 0; j < 4; ++j) {
            const int col = col0 + j * 16;
            bs[j] = b1[col];
            if (b2) bs[j] += b2[col];
        }
#pragma unroll
        for (int i = 0; i < 4; ++i)
#pragma unroll
            for (int j = 0; j < 4; ++j)
#pragma unroll
                for (int rg = 0; rg < 4; ++rg)
                    C[(size_t)(row0 + i * 16 + rg) * N + col0 + j * 16] = acc[i][j][rg] + bs[j];

        if (part) {
            float pm[4][4], ps[4][4];
#pragma unroll
            for (int i = 0; i < 4; ++i)
#pragma unroll
                for (int rg = 0; rg < 4; ++rg) {
                    float m = acc[i][0][rg] + bs[0];
                    m = fmaxf(m, acc[i][1][rg] + bs[1]);
                    m = fmaxf(m, acc[i][2][rg] + bs[2]);
                    m = fmaxf(m, acc[i][3][rg] + bs[3]);
                    pm[i][rg] = m;
                }
#pragma unroll
            for (int mask = 1; mask <= 8; mask <<= 1)
#pragma unroll
                for (int i = 0; i < 4; ++i)
#pragma unroll
                    for (int rg = 0; rg < 4; ++rg)
                        pm[i][rg] = fmaxf(pm[i][rg], __shfl_xor(pm[i][rg], mask));
#pragma unroll
            for (int i = 0; i < 4; ++i)
#pragma unroll
                for (int rg = 0; rg < 4; ++rg) {
                    float s = 0.f;
#pragma unroll
                    for (int j = 0; j < 4; ++j)
                        s += expf(acc[i][j][rg] + bs[j] - pm[i][rg]);
                    ps[i][rg] = s;
                }
#pragma unroll
            for (int mask = 1; mask <= 8; mask <<= 1)
#pragma unroll
                for (int i = 0; i < 4; ++i)
#pragma unroll
                    for (int rg = 0; rg < 4; ++rg)
                        ps[i][rg] += __shfl_xor(ps[i][rg], mask);
            if ((lane & 15) == 0) {
#pragma unroll
                for (int i = 0; i < 4; ++i)
#pragma unroll
                    for (int rg = 0; rg < 4; ++rg) {
                        const int r64 = ((lane >> 4) << 2) + i * 16 + rg;
                        prt[wn][wm * 64 + r64][0] = pm[i][rg];
                        prt[wn][wm * 64 + r64][1] = ps[i][rg];
                    }
            }
            __syncthreads();
            if (tid < 128) {
                const float m0_ = prt[0][tid][0], s0_ = prt[0][tid][1];
                const float m1_ = prt[1][tid][0], s1_ = prt[1][tid][1];
                const float Mx = fmaxf(m0_, m1_);
                const float Sx = s0_ * expf(m0_ - Mx) + s1_ * expf(m1_ - Mx);
                const size_t o = ((size_t)(bm + tid) * nTN + (bn >> 7)) * 2;
                part[o] = Mx; part[o + 1] = Sx;
            }
        }
    } else {
        const int tblk = (bm >> 6) + wm;
        const int rb = (lane >> 4) << 2;
#pragma unroll
        for (int i = 0; i < 4; ++i) {
#pragma unroll
            for (int j = 0; j < 4; ++j) {
                const int col = col0 + j * 16;
                float bias = b1[col];
                if (b2) bias += b2[col];
                float4 v = { acc[i][j][0] + bias, acc[i][j][1] + bias,
                             acc[i][j][2] + bias, acc[i][j][3] + bias };
                *reinterpret_cast<float4*>(&C[((size_t)tblk * N + col) * 64 + rb + i * 16]) = v;
            }
        }
    }
}

// ---------------- persistent MFMA LSTM scan, WAVE-SCOPED producer polling ----------------
// Grid 256x256. hist: (T,B,1024) bf16. xw: fp32 (T, 4096, B).
// Staging remapped so wave w owns chunk-cols [w*CPW,(w+1)*CPW) whose producers are
// exactly blocks [w*2CPW,(w+1)*2CPW) of the dir: each wave polls ONLY its own 2*CPW
// producer flags (one per lane, wave-__all loop) then stages immediately — no block-wide
// AND before staging. Block-wide LDS consistency via the existing pre-MFMA barrier.
// Producer protocol unchanged: h-stores -> vmcnt(0) (wave 0) -> flag store.
template<int H_T>
__global__ __launch_bounds__(256, 1) void lstm_mfma_scan(
    const float* __restrict__ xw0, const float* __restrict__ xw1,
    const float* __restrict__ Whh0, const float* __restrict__ Whh1,
    const unsigned short* __restrict__ h0b, const float* __restrict__ c0,
    unsigned short* __restrict__ hist,
    unsigned short* __restrict__ hsb, float* __restrict__ csd,
    int T, int ndir, int rev_mask, int* bar)
{
    constexpr int KST = H_T / 32;
    constexpr int CH  = H_T / 8;         // 16B chunks per h row
    constexpr int CPW = CH / 4;          // chunk-cols per wave (16 enc / 32 dec)
    constexpr int NB  = CPW / 8;         // staging batches of 8 chunks (2 enc / 4 dec)

    __shared__ __align__(16) unsigned short h_lds[64 * H_T];
    __shared__ float pre[64][17];
    __shared__ __align__(8) unsigned short hpack[64][4];

    const int tid  = threadIdx.x;
    const int lane = tid & 63;
    const int w    = tid >> 6;
    const int bpd  = (ndir == 2) ? 128 : 256;
    const int dir  = blockIdx.x / bpd;
    const int blk  = blockIdx.x - dir * bpd;
    const int m0   = blk * 4;
    const int rev  = (rev_mask >> dir) & 1;
    const float* xw  = dir ? xw1  : xw0;
    const float* Whh = dir ? Whh1 : Whh0;
    const int dcol = dir * H_T;
    const int b = tid & 63;
    const int j = tid >> 6;

    int* myflag = bar + blockIdx.x * 32;
    // this wave's producer set: blocks [w*2CPW, (w+1)*2CPW) of this dir; one per lane
    const int* pflag = bar + (dir * bpd + w * 2 * CPW + (lane % (2 * CPW))) * 32;
    // this thread's staging chunks: col = w*CPW + lane%CPW; rows (lane/CPW)*CPW + i
    const int scc = w * CPW + (lane % CPW);
    const int sr0 = (lane / CPW) * CPW;

    // ---- B-fragments: Whh rows in registers, bf16 ----
    const int n  = lane & 15;           // (gate,cell) = (n>>2, n&3)
    const int kg = lane >> 4;
    const int wr = (n >> 2) * H_T + m0 + (n & 3);
    s16x8 wfr[KST];
#pragma unroll
    for (int ks = 0; ks < KST; ++ks) {
        const float* wp = Whh + (size_t)wr * H_T + ks * 32 + kg * 8;
        const float4 lo = *reinterpret_cast<const float4*>(wp);
        const float4 hi = *reinterpret_cast<const float4*>(wp + 4);
        s16x8 rr;
        rr[0] = (short)f2bf(lo.x); rr[1] = (short)f2bf(lo.y);
        rr[2] = (short)f2bf(lo.z); rr[3] = (short)f2bf(lo.w);
        rr[4] = (short)f2bf(hi.x); rr[5] = (short)f2bf(hi.y);
        rr[6] = (short)f2bf(hi.z); rr[7] = (short)f2bf(hi.w);
        wfr[ks] = rr;
    }

    float c  = c0 ? c0[(size_t)b * HSTR + dcol + m0 + j] : 0.f;
    float hn = 0.f;
    const int rA  = w * 16 + n;
    const int rAx = rA & 7;

    for (int s = 0; s < T; ++s) {
        const int tt = rev ? (T - 1 - s) : s;

        // coalesced xw gate loads: layout (tt, 4096, b)
        const float* xb = xw + ((size_t)tt * 4096 + m0 + j) * 64 + b;
        float xg0 = g_load1(xb);
        float xg1 = g_load1(xb + (size_t)H_T * 64);
        float xg2 = g_load1(xb + (size_t)2 * H_T * 64);
        float xg3 = g_load1(xb + (size_t)3 * H_T * 64);

        // wave-scoped poll: wait only for THIS wave's producers of step s-1
        if (s > 0) {
            for (;;) {
                const int f = sc_load1(pflag);
                if (__all(f >= s)) break;
            }
        }

        const unsigned short* hb;
        size_t tofs;
        if (s == 0) { hb = h0b; tofs = 0; }
        else {
            const int tp = rev ? (tt + 1) : (tt - 1);
            hb = hist; tofs = (size_t)tp * (64 * 1024);
        }

        float p0 = 0.f, p1 = 0.f, p2 = 0.f, p3 = 0.f;
        if (hb) {
            // ---- stage this wave's chunk-cols: sc_load4 -> XOR-swizzled LDS ----
            const unsigned short* src = hb + tofs + dcol + scc * 8;
            f4_t bufA[8], bufB[8];
            auto issue = [&](f4_t (&bf)[8], int bt) {
#pragma unroll
                for (int jj = 0; jj < 8; ++jj) {
                    const int rr_ = sr0 + bt * 8 + jj;
                    bf[jj] = sc_load4(src + (size_t)rr_ * 1024);
                }
            };
            auto writeb = [&](const f4_t (&bf)[8], int bt) {
#pragma unroll
                for (int jj = 0; jj < 8; ++jj) {
                    const int rr_ = sr0 + bt * 8 + jj;
                    const int off = rr_ * (2 * H_T) + ((scc ^ (rr_ & 7)) << 4);
                    *(f4_t*)((char*)h_lds + off) = bf[jj];
                }
            };
            issue(bufA, 0);
            if (NB > 1) issue(bufB, 1);
#pragma unroll
            for (int bt = 0; bt < NB; ++bt) {
                if (bt + 1 < NB) wait_vm8(); else wait_vm0();
                if (bt & 1) writeb(bufB, bt); else writeb(bufA, bt);
                if (bt + 2 < NB) { if (bt & 1) issue(bufB, bt + 2); else issue(bufA, bt + 2); }
            }
            __syncthreads();

            // ---- MFMA: D[batch][n] += h[batch][k] * W[wr(n)][k] ----
            f32x4 acc = {0.f, 0.f, 0.f, 0.f};
#pragma unroll
            for (int ks = 0; ks < KST; ++ks) {
                const int cc_ = ks * 4 + kg;
                const int off = rA * (2 * H_T) + ((cc_ ^ rAx) << 4);
                const bf16x8 a = __builtin_bit_cast(bf16x8,
                    *(const s16x8*)((const char*)h_lds + off));
                acc = __builtin_amdgcn_mfma_f32_16x16x32_bf16(
                    a, __builtin_bit_cast(bf16x8, wfr[ks]), acc, 0, 0, 0);
            }
            // ---- exchange D -> (b, gate) layout ----
#pragma unroll
            for (int rg = 0; rg < 4; ++rg)
                pre[w * 16 + kg * 4 + rg][n] = acc[rg];
            __syncthreads();
            p0 = pre[b][0 + j]; p1 = pre[b][4 + j];
            p2 = pre[b][8 + j]; p3 = pre[b][12 + j];
        }

        asm volatile("s_waitcnt vmcnt(0)"
                     : "+v"(xg0), "+v"(xg1), "+v"(xg2), "+v"(xg3) :: "memory");

        const float ig = sigmoidf_(p0 + xg0);
        const float fg = sigmoidf_(p1 + xg1);
        const float gg = tanhf(p2 + xg2);
        const float og = sigmoidf_(p3 + xg3);
        c  = fg * c + ig * gg;
        hn = og * tanhf(c);

        // pack 4 cells x 64 batches in LDS -> 64 coherent 8B stores (wave 0)
        hpack[b][j] = f2bf(hn);
        __syncthreads();
        if (tid < 64) {
            const i32x2 v2 = *reinterpret_cast<const i32x2*>(&hpack[tid][0]);
            sc_store8(hist + (size_t)tt * (64 * 1024) + (size_t)tid * 1024 + dcol + m0, v2);
        }
        wait_vm0();               // wave 0: its own 64 h-stores drained before its flag
        if (s + 1 < T && tid == 0) sc_store_int(myflag, s + 1);
    }

    if (hsb) hsb[(size_t)b * 1024 + dcol + m0 + j] = f2bf(hn);
    if (csd) csd[(size_t)b * HSTR + dcol + m0 + j] = c;
}

// ---------------- log-softmax: merge partials + normalize, one kernel ----------------
__global__ __launch_bounds__(256) void lsm_norm_kernel(
    float* __restrict__ x, const float* __restrict__ part, int nt, int n4)
{
    __shared__ float ms[256], ss[256];
    const int tid = threadIdx.x;
    float m = -3.0e38f, s = 0.f;
    for (int t = tid; t < nt; t += 256) {
        const float mo = part[((size_t)blockIdx.x * nt + t) * 2];
        const float so = part[((size_t)blockIdx.x * nt + t) * 2 + 1];
        const float M = fmaxf(m, mo);
        s = s * expf(m - M) + so * expf(mo - M);
        m = M;
    }
    ms[tid] = m; ss[tid] = s;
    __syncthreads();
    for (int off = 128; off > 0; off >>= 1) {
        if (tid < off) {
            const float m2 = ms[tid + off], s2 = ss[tid + off];
            const float m1 = ms[tid],       s1 = ss[tid];
            const float M = fmaxf(m1, m2);
            ss[tid] = s1 * expf(m1 - M) + s2 * expf(m2 - M);
            ms[tid] = M;
        }
        __syncthreads();
    }
    const float ML = ms[0] + logf(ss[0]);
    float4* p = reinterpret_cast<float4*>(x + (size_t)blockIdx.x * (n4 * 4));
    for (int cc = tid; cc < n4; cc += 256) {
        float4 v = p[cc];
        v.x -= ML; v.y -= ML; v.z -= ML; v.w -= ML;
        p[cc] = v;
    }
}

// ---------------- host-side orchestration ----------------
extern "C" void kernel_launch(void* const* d_in, const int* in_sizes, int n_in,
                              void* d_out, int out_size, void* d_ws, size_t ws_size,
                              hipStream_t stream)
{
    const int*   sent  = (const int*)d_in[0];
    const int*   targ  = (const int*)d_in[1];
    const float* emb   = (const float*)d_in[2];
    const float* e0Wih = (const float*)d_in[3];
    const float* e0Whh = (const float*)d_in[4];
    const float* e0bih = (const float*)d_in[5];
    const float* e0bhh = (const float*)d_in[6];
    const float* e1Wih = (const float*)d_in[7];
    const float* e1Whh = (const float*)d_in[8];
    const float* e1bih = (const float*)d_in[9];
    const float* e1bhh = (const float*)d_in[10];
    const float* d0Wih = (const float*)d_in[11];
    const float* d0Whh = (const float*)d_in[12];
    const float* d0bih = (const float*)d_in[13];
    const float* d0bhh = (const float*)d_in[14];
    const float* d1Wih = (const float*)d_in[15];
    const float* d1Whh = (const float*)d_in[16];
    const float* d1bih = (const float*)d_in[17];
    const float* d1bhh = (const float*)d_in[18];
    const float* Wout  = (const float*)d_in[19];
    const float* bout  = (const float*)d_in[20];

    float* ws  = (float*)d_ws;
    float* xwA = ws + WS_XWA;
    float* xwB = ws + WS_XWB;
    float* cs  = ws + WS_CS;
    int*   bar = (int*)(ws + WS_BAR);
    unsigned short* ub    = (unsigned short*)(ws + WS_BF);
    unsigned short* x0b   = ub + U_X0B;
    unsigned short* h_e0  = ub + U_HE0;
    unsigned short* h_e1  = ub + U_HE1;
    unsigned short* h_d0  = ub + U_HD0;
    unsigned short* h_d1  = ub + U_HD1;
    unsigned short* hsb   = ub + U_HSB;
    unsigned short* e0Wb  = ub + U_E0W;
    unsigned short* e1Wb  = ub + U_E1W;
    unsigned short* d0Wb  = ub + U_D0W;
    unsigned short* d1Wb  = ub + U_D1W;
    unsigned short* Woutb = (unsigned short*)xwA;
    float* out = (float*)d_out;

    hipMemsetAsync(bar, 0, 4 * 8192 * sizeof(int), stream);

    // ---- weight conversions (fp32 -> bf16), one kernel ----
    f2b_multi_kernel<<<1280, 256, 0, stream>>>(e0Wih, e0Wb, e1Wih, e1Wb,
                                               d0Wih, d0Wb, d1Wih, d1Wb);

    // ---- encoder layer 0 (both dirs in ONE GEMM: N=4096, dir1 cols at 2048) ----
    embed_src_kernel<<<(S_LEN * BSZ) / 4, 256, 0, stream>>>(sent, emb, x0b);
    gemm_bf16_kernel<<<64 * 32, 256, 0, stream>>>(x0b, e0Wb, e0bih, e0bhh, xwA,
                                                  S_LEN * BSZ, 4096, EMBD, 32, 1, nullptr);
    lstm_mfma_scan<512><<<256, 256, 0, stream>>>(xwA, xwA + 2048 * 64,
                                                 e0Whh, e0Whh + 2048ull * 512,
                                                 nullptr, nullptr, h_e0,
                                                 hsb, cs, S_LEN, 2, 2, bar);
    // ---- encoder layer 1 (final states only) ----
    gemm_bf16_kernel<<<64 * 32, 256, 0, stream>>>(h_e0, e1Wb, e1bih, e1bhh, xwA,
                                                  S_LEN * BSZ, 4096, 2 * HID_, 32, 1, nullptr);
    lstm_mfma_scan<512><<<256, 256, 0, stream>>>(xwA, xwA + 2048 * 64,
                                                 e1Whh, e1Whh + 2048ull * 512,
                                                 nullptr, nullptr, h_e1,
                                                 hsb + 65536, cs + 65536,
                                                 S_LEN, 2, 2, bar + 8192);
    // ---- decoder layer 0 ----
    embed_dec_kernel<<<(T_LEN * BSZ) / 4, 256, 0, stream>>>(sent, targ, emb, x0b);
    gemm_bf16_kernel<<<32 * 32, 256, 0, stream>>>(x0b, d0Wb, d0bih, d0bhh, xwA,
                                                  T_LEN * BSZ, 4 * DHID_, EMBD, 32, 1, nullptr);
    lstm_mfma_scan<1024><<<256, 256, 0, stream>>>(xwA, nullptr, d0Whh, nullptr,
                                                  hsb, cs, h_d0,
                                                  nullptr, nullptr, T_LEN, 1, 0,
                                                  bar + 2 * 8192);
    // ---- Wout -> bf16 (xwA region free after dec0 scan) ----
    f2b_kernel<<<2048, 256, 0, stream>>>(Wout, Woutb, (VOC_ * DHID_) / 4);
    // ---- decoder layer 1 ----
    gemm_bf16_kernel<<<32 * 32, 256, 0, stream>>>(h_d0, d1Wb, d1bih, d1bhh, xwB,
                                                  T_LEN * BSZ, 4 * DHID_, DHID_, 32, 1, nullptr);
    lstm_mfma_scan<1024><<<256, 256, 0, stream>>>(xwB, nullptr, d1Whh, nullptr,
                                                  hsb + 65536, cs + 65536, h_d1,
                                                  nullptr, nullptr, T_LEN, 1, 0,
                                                  bar + 3 * 8192);
    // ---- vocab projection (fused softmax partials) + merge+normalize ----
    gemm_bf16_kernel<<<32 * 250, 256, 0, stream>>>(h_d1, Woutb, bout, nullptr, out,
                                                   T_LEN * BSZ, VOC_, DHID_, 250, 0, xwB);
    lsm_norm_kernel<<<T_LEN * BSZ, 256, 0, stream>>>(out, xwB, 250, VOC_ / 4);
}